// Round 1
// baseline (19690.462 us; speedup 1.0000x reference)
//
#include <hip/hip_runtime.h>
#include <hip/hip_bf16.h>

#define NNODES 131072
#define LGRAPH 256
#define BGRAPH 512
#define DIN 300
#define DH 96
#define EPG 2048
#define VOCAB 50001
#define NCLS 20
#define NEG 0.2f

__device__ __forceinline__ float bf2f(__hip_bfloat16 h) { return __bfloat162float(h); }
__device__ __forceinline__ __hip_bfloat16 f2bf(float f) { return __float2bfloat16(f); }
__device__ __forceinline__ float dot4(float4 a, float4 b) {
  return a.x*b.x + a.y*b.y + a.z*b.z + a.w*b.w;
}
__device__ __forceinline__ float sigm(float v) { return 1.f / (1.f + __expf(-v)); }
// order-preserving float<->uint encode for atomicMax
__device__ __forceinline__ unsigned fenc(float f) {
  unsigned u = __float_as_uint(f);
  return (u & 0x80000000u) ? ~u : (u | 0x80000000u);
}
__device__ __forceinline__ float fdec(unsigned u) {
  return __uint_as_float((u & 0x80000000u) ? (u & 0x7fffffffu) : ~u);
}

// T[VOCAB][96] = embed[VOCAB][300] @ We[300][96]
__global__ __launch_bounds__(512) void k_embed_mm(
    const float* __restrict__ embed, const float* __restrict__ We,
    float* __restrict__ T) {
  __shared__ float sW[DH * DIN];   // transposed [c][k]
  __shared__ float sE[8][DIN];
  const int t = threadIdx.x;
  for (int i = t; i < DH * DIN; i += 512) {
    int c = i / DIN, k = i - c * DIN;
    sW[i] = We[k * DH + c];
  }
  __syncthreads();
  const int c = t & 127, rg = t >> 7;
  const int cc = (c < DH) ? c : 0;
  for (int base = blockIdx.x * 8; base < VOCAB; base += gridDim.x * 8) {
    for (int i = t; i < 8 * DIN; i += 512) {
      int rr = i / DIN, kk = i - rr * DIN;
      int row = base + rr;
      sE[rr][kk] = (row < VOCAB) ? embed[row * DIN + kk] : 0.f;
    }
    __syncthreads();
    if (c < DH) {
      const int r0 = rg * 2, r1 = r0 + 1;
      float acc0 = 0.f, acc1 = 0.f;
      for (int k = 0; k < DIN; k += 4) {
        float4 w = *(const float4*)&sW[cc * DIN + k];
        float4 e0 = *(const float4*)&sE[r0][k];
        float4 e1 = *(const float4*)&sE[r1][k];
        acc0 += dot4(w, e0);
        acc1 += dot4(w, e1);
      }
      if (base + r0 < VOCAB) T[(base + r0) * DH + cc] = acc0;
      if (base + r1 < VOCAB) T[(base + r1) * DH + cc] = acc1;
    }
    __syncthreads();
  }
}

// x[n][c] = tanh(T[ids[n]][c] + be[c])
__global__ void k_gather(const int* __restrict__ ids, const float* __restrict__ T,
                         const float* __restrict__ be, float* __restrict__ x) {
  const int total = NNODES * (DH / 4);
  for (int i = blockIdx.x * blockDim.x + threadIdx.x; i < total;
       i += gridDim.x * blockDim.x) {
    int n = i / (DH / 4);
    int q = i - n * (DH / 4);
    float4 v = ((const float4*)T)[ids[n] * (DH / 4) + q];
    float4 b = ((const float4*)be)[q];
    float4 o;
    o.x = tanhf(v.x + b.x); o.y = tanhf(v.y + b.y);
    o.z = tanhf(v.z + b.z); o.w = tanhf(v.w + b.w);
    ((float4*)x)[i] = o;
  }
}

// h = x@Wg (bf16 out) ; a_s = h@att_src ; a_d = h@att_dst
__global__ __launch_bounds__(512) void k_h(
    const float* __restrict__ x, const float* __restrict__ Wg,
    const float* __restrict__ att_s, const float* __restrict__ att_d,
    __hip_bfloat16* __restrict__ h, float* __restrict__ a_s,
    float* __restrict__ a_d) {
  __shared__ float sW[DH * DH];
  __shared__ float sx[8][DH];
  __shared__ float sas[DH], sad[DH];
  __shared__ float red[4][2][4];
  const int t = threadIdx.x;
  for (int i = t; i < DH * DH; i += 512) {
    int c = i / DH, k = i - c * DH;
    sW[i] = Wg[k * DH + c];
  }
  if (t < DH) { sas[t] = att_s[t]; sad[t] = att_d[t]; }
  __syncthreads();
  const int c = t & 127, rg = t >> 7;
  const int cc = (c < DH) ? c : 0;
  const int lane = t & 63, half = (t >> 6) & 1;
  for (int base = blockIdx.x * 8; base < NNODES; base += gridDim.x * 8) {
    for (int i = t; i < 8 * DH; i += 512) {
      int rr = i / DH;
      sx[rr][i - rr * DH] = x[base * DH + i];
    }
    __syncthreads();
    float acc0 = 0.f, acc1 = 0.f;
    const int r0 = rg * 2, r1 = r0 + 1;
    if (c < DH) {
      #pragma unroll
      for (int k = 0; k < DH; k += 4) {
        float4 w = *(const float4*)&sW[cc * DH + k];
        float4 e0 = *(const float4*)&sx[r0][k];
        float4 e1 = *(const float4*)&sx[r1][k];
        acc0 += dot4(w, e0);
        acc1 += dot4(w, e1);
      }
      h[(base + r0) * DH + cc] = f2bf(acc0);
      h[(base + r1) * DH + cc] = f2bf(acc1);
    }
    float v0s = (c < DH) ? acc0 * sas[cc] : 0.f;
    float v0d = (c < DH) ? acc0 * sad[cc] : 0.f;
    float v1s = (c < DH) ? acc1 * sas[cc] : 0.f;
    float v1d = (c < DH) ? acc1 * sad[cc] : 0.f;
    #pragma unroll
    for (int o = 32; o > 0; o >>= 1) {
      v0s += __shfl_down(v0s, o);
      v0d += __shfl_down(v0d, o);
      v1s += __shfl_down(v1s, o);
      v1d += __shfl_down(v1d, o);
    }
    if (lane == 0) {
      red[rg][half][0] = v0s; red[rg][half][1] = v0d;
      red[rg][half][2] = v1s; red[rg][half][3] = v1d;
    }
    __syncthreads();
    if (t < 8) {
      int rgi = t >> 1, wh = t & 1;
      int n = base + rgi * 2 + wh;
      a_s[n] = red[rgi][0][wh * 2 + 0] + red[rgi][1][wh * 2 + 0];
      a_d[n] = red[rgi][0][wh * 2 + 1] + red[rgi][1][wh * 2 + 1];
    }
    __syncthreads();
  }
}

// per-graph GAT softmax + aggregation: a[n][c] = sum alpha * h[src][c] + bg[c]
__global__ __launch_bounds__(256) void k_att(
    const int* __restrict__ src, const int* __restrict__ dst,
    const __hip_bfloat16* __restrict__ h, const float* __restrict__ a_sg,
    const float* __restrict__ a_dg, const float* __restrict__ bg,
    float* __restrict__ aout) {
  __shared__ float s_as[LGRAPH], s_ad[LGRAPH], s_den[LGRAPH];
  __shared__ unsigned s_m[LGRAPH];
  __shared__ float s_e[EPG];
  __shared__ unsigned char s_sl[EPG], s_dl[EPG];
  __shared__ float s_bg[DH];
  __shared__ float s_a[LGRAPH * DH];   // 96 KB
  const int g = blockIdx.x, t = threadIdx.x;
  const int nb = g * LGRAPH;
  {
    float as = a_sg[nb + t], ad = a_dg[nb + t];
    s_as[t] = as; s_ad[t] = ad;
    float se = as + ad; se = se > 0.f ? se : NEG * se;   // self-loop logit
    s_m[t] = fenc(se);
  }
  if (t < DH) s_bg[t] = bg[t];
  for (int e = t; e < EPG; e += 256) {
    s_sl[e] = (unsigned char)(src[g * EPG + e] - nb);
    s_dl[e] = (unsigned char)(dst[g * EPG + e] - nb);
  }
  __syncthreads();
  // phase 1: edge logits + segment max
  for (int e = t; e < EPG; e += 256) {
    int sl = s_sl[e], dl = s_dl[e];
    float ee = s_as[sl] + s_ad[dl];
    ee = ee > 0.f ? ee : NEG * ee;
    s_e[e] = ee;
    atomicMax(&s_m[dl], fenc(ee));
  }
  __syncthreads();
  // phase 2a: denom init with self term; stash m as float bits
  {
    float m = fdec(s_m[t]);
    float se = s_as[t] + s_ad[t]; se = se > 0.f ? se : NEG * se;
    s_den[t] = __expf(se - m);
    s_m[t] = __float_as_uint(m);
  }
  __syncthreads();
  // phase 2b: exp + denom accumulate
  for (int e = t; e < EPG; e += 256) {
    int dl = s_dl[e];
    float ex = __expf(s_e[e] - __uint_as_float(s_m[dl]));
    s_e[e] = ex;
    atomicAdd(&s_den[dl], ex);
  }
  __syncthreads();
  // phase 2c: normalize; self alpha into s_as
  {
    float m = __uint_as_float(s_m[t]);
    float se = s_as[t] + s_ad[t]; se = se > 0.f ? se : NEG * se;
    float sa = __expf(se - m) / s_den[t];
    __syncthreads();            // ensure all reads of s_as done before overwrite
    s_as[t] = sa;
  }
  for (int e = t; e < EPG; e += 256) s_e[e] /= s_den[s_dl[e]];
  __syncthreads();
  const int wv = t >> 6, ln = t & 63;
  // phase 3a: self init (direct store)
  for (int i = wv; i < LGRAPH; i += 4) {
    float al = s_as[i];
    const __hip_bfloat16* hp = &h[(nb + i) * DH];
    float* ap = &s_a[i * DH];
    ap[ln] = al * bf2f(hp[ln]);
    if (ln < DH - 64) ap[64 + ln] = al * bf2f(hp[64 + ln]);
  }
  __syncthreads();
  // phase 3b: edge scatter-add
  for (int e = wv; e < EPG; e += 4) {
    float al = s_e[e];
    int dl = s_dl[e], sl = s_sl[e];
    const __hip_bfloat16* hp = &h[(nb + sl) * DH];
    float* ap = &s_a[dl * DH];
    atomicAdd(&ap[ln], al * bf2f(hp[ln]));
    if (ln < DH - 64) atomicAdd(&ap[64 + ln], al * bf2f(hp[64 + ln]));
  }
  __syncthreads();
  // phase 4: write out + bg
  for (int i = wv; i < LGRAPH; i += 4) {
    const float* ap = &s_a[i * DH];
    float* og = &aout[(nb + i) * DH];
    og[ln] = ap[ln] + s_bg[ln];
    if (ln < DH - 64) og[64 + ln] = ap[64 + ln] + s_bg[64 + ln];
  }
}

// r gate: u = x * sigmoid(a@Wr0 + x@Wr1 + br0 + br1)   (bf16 out)
__global__ __launch_bounds__(512) void k_gates(
    const float* __restrict__ a, const float* __restrict__ x,
    const float* __restrict__ Wr0, const float* __restrict__ br0,
    const float* __restrict__ Wr1, const float* __restrict__ br1,
    __hip_bfloat16* __restrict__ u) {
  __shared__ float sW0[DH * DH], sW1[DH * DH];
  __shared__ float sa[8][DH], sx[8][DH];
  const int t = threadIdx.x;
  for (int i = t; i < DH * DH; i += 512) {
    int c = i / DH, k = i - c * DH;
    sW0[i] = Wr0[k * DH + c];
    sW1[i] = Wr1[k * DH + c];
  }
  __syncthreads();
  const int c = t & 127, rg = t >> 7;
  const int cc = (c < DH) ? c : 0;
  for (int base = blockIdx.x * 8; base < NNODES; base += gridDim.x * 8) {
    for (int i = t; i < 8 * DH; i += 512) {
      int rr = i / DH, kk = i - rr * DH;
      sa[rr][kk] = a[base * DH + i];
      sx[rr][kk] = x[base * DH + i];
    }
    __syncthreads();
    if (c < DH) {
      const int r0 = rg * 2, r1 = r0 + 1;
      float ar0 = 0, ar1 = 0, xr0 = 0, xr1 = 0;
      #pragma unroll
      for (int k = 0; k < DH; k += 4) {
        float4 w0 = *(const float4*)&sW0[cc * DH + k];
        float4 w1 = *(const float4*)&sW1[cc * DH + k];
        float4 a0 = *(const float4*)&sa[r0][k];
        float4 a1 = *(const float4*)&sa[r1][k];
        float4 x0 = *(const float4*)&sx[r0][k];
        float4 x1 = *(const float4*)&sx[r1][k];
        ar0 += dot4(w0, a0); ar1 += dot4(w0, a1);
        xr0 += dot4(w1, x0); xr1 += dot4(w1, x1);
      }
      float rb = br0[cc] + br1[cc];
      float rv0 = sigm(ar0 + xr0 + rb);
      float rv1 = sigm(ar1 + xr1 + rb);
      u[(base + r0) * DH + cc] = f2bf(sx[r0][cc] * rv0);
      u[(base + r1) * DH + cc] = f2bf(sx[r1][cc] * rv1);
    }
    __syncthreads();
  }
}

// z = sigmoid(a@Wz0 + x@Wz1 + b), hh = tanh(a@Wh0 + u@Wh1 + b), x = hh z + x(1-z)
__global__ __launch_bounds__(512) void k_fin(
    const float* __restrict__ a, const __hip_bfloat16* __restrict__ u,
    float* x,
    const float* __restrict__ Wz0, const float* __restrict__ bz0,
    const float* __restrict__ Wz1, const float* __restrict__ bz1,
    const float* __restrict__ Wh0, const float* __restrict__ bh0,
    const float* __restrict__ Wh1, const float* __restrict__ bh1) {
  __shared__ float sWz0[DH * DH], sWz1[DH * DH], sWh0[DH * DH], sWh1[DH * DH];
  __shared__ float sa[8][DH], sx[8][DH], su[8][DH];
  const int t = threadIdx.x;
  for (int i = t; i < DH * DH; i += 512) {
    int c = i / DH, k = i - c * DH;
    sWz0[i] = Wz0[k * DH + c]; sWz1[i] = Wz1[k * DH + c];
    sWh0[i] = Wh0[k * DH + c]; sWh1[i] = Wh1[k * DH + c];
  }
  __syncthreads();
  const int c = t & 127, rg = t >> 7;
  const int cc = (c < DH) ? c : 0;
  for (int base = blockIdx.x * 8; base < NNODES; base += gridDim.x * 8) {
    for (int i = t; i < 8 * DH; i += 512) {
      int rr = i / DH, kk = i - rr * DH;
      sa[rr][kk] = a[base * DH + i];
      sx[rr][kk] = x[base * DH + i];
      su[rr][kk] = bf2f(u[base * DH + i]);
    }
    __syncthreads();
    if (c < DH) {
      const int r0 = rg * 2, r1 = r0 + 1;
      float za0 = 0, za1 = 0, zx0 = 0, zx1 = 0, ha0 = 0, ha1 = 0, hu0 = 0, hu1 = 0;
      #pragma unroll
      for (int k = 0; k < DH; k += 4) {
        float4 wz0 = *(const float4*)&sWz0[cc * DH + k];
        float4 wz1 = *(const float4*)&sWz1[cc * DH + k];
        float4 wh0 = *(const float4*)&sWh0[cc * DH + k];
        float4 wh1 = *(const float4*)&sWh1[cc * DH + k];
        float4 a0 = *(const float4*)&sa[r0][k];
        float4 a1 = *(const float4*)&sa[r1][k];
        float4 x0 = *(const float4*)&sx[r0][k];
        float4 x1 = *(const float4*)&sx[r1][k];
        float4 u0 = *(const float4*)&su[r0][k];
        float4 u1 = *(const float4*)&su[r1][k];
        za0 += dot4(wz0, a0); za1 += dot4(wz0, a1);
        zx0 += dot4(wz1, x0); zx1 += dot4(wz1, x1);
        ha0 += dot4(wh0, a0); ha1 += dot4(wh0, a1);
        hu0 += dot4(wh1, u0); hu1 += dot4(wh1, u1);
      }
      float zb = bz0[cc] + bz1[cc], hb = bh0[cc] + bh1[cc];
      float z0 = sigm(za0 + zx0 + zb), z1 = sigm(za1 + zx1 + zb);
      float hh0 = tanhf(ha0 + hu0 + hb), hh1 = tanhf(ha1 + hu1 + hb);
      float xi0 = sx[r0][cc], xi1 = sx[r1][cc];
      x[(base + r0) * DH + cc] = hh0 * z0 + xi0 * (1.f - z0);
      x[(base + r1) * DH + cc] = hh1 * z1 + xi1 * (1.f - z1);
    }
    __syncthreads();
  }
}

// y = tanh(x@Wemb); pooled = max_l + mean_l; out = pooled @ Wmlp
__global__ __launch_bounds__(512) void k_readout(
    const float* __restrict__ x, const float* __restrict__ Wemb,
    const float* __restrict__ Wmlp, float* __restrict__ out) {
  __shared__ float sW[DH * DH];
  __shared__ float sx[8][DH];
  __shared__ float rmax[4][DH], rsum[4][DH];
  __shared__ float spool[DH];
  const int g = blockIdx.x, t = threadIdx.x;
  for (int i = t; i < DH * DH; i += 512) {
    int c = i / DH, k = i - c * DH;
    sW[i] = Wemb[k * DH + c];
  }
  __syncthreads();
  const int c = t & 127, rg = t >> 7;
  const int cc = (c < DH) ? c : 0;
  float mymax = -1e30f, mysum = 0.f;
  for (int base = 0; base < LGRAPH; base += 8) {
    for (int i = t; i < 8 * DH; i += 512) {
      int rr = i / DH;
      sx[rr][i - rr * DH] = x[(g * LGRAPH + base) * DH + i];
    }
    __syncthreads();
    if (c < DH) {
      const int r0 = rg * 2, r1 = r0 + 1;
      float acc0 = 0.f, acc1 = 0.f;
      #pragma unroll
      for (int k = 0; k < DH; k += 4) {
        float4 w = *(const float4*)&sW[cc * DH + k];
        float4 e0 = *(const float4*)&sx[r0][k];
        float4 e1 = *(const float4*)&sx[r1][k];
        acc0 += dot4(w, e0);
        acc1 += dot4(w, e1);
      }
      float y0 = tanhf(acc0), y1 = tanhf(acc1);
      mymax = fmaxf(mymax, fmaxf(y0, y1));
      mysum += y0 + y1;
    }
    __syncthreads();
  }
  if (c < DH) { rmax[rg][cc] = mymax; rsum[rg][cc] = mysum; }
  __syncthreads();
  if (t < DH) {
    float mx = fmaxf(fmaxf(rmax[0][t], rmax[1][t]), fmaxf(rmax[2][t], rmax[3][t]));
    float sm = rsum[0][t] + rsum[1][t] + rsum[2][t] + rsum[3][t];
    spool[t] = mx + sm * (1.f / LGRAPH);
  }
  __syncthreads();
  if (t < NCLS) {
    float acc = 0.f;
    for (int k = 0; k < DH; ++k) acc += spool[k] * Wmlp[k * NCLS + t];
    out[g * NCLS + t] = acc;
  }
}

extern "C" void kernel_launch(void* const* d_in, const int* in_sizes, int n_in,
                              void* d_out, int out_size, void* d_ws, size_t ws_size,
                              hipStream_t stream) {
  const int*   node_ids = (const int*)d_in[0];
  const int*   src      = (const int*)d_in[1];
  const int*   dst      = (const int*)d_in[2];
  const float* embed    = (const float*)d_in[3];
  const float* We   = (const float*)d_in[4];
  const float* be   = (const float*)d_in[5];
  const float* Wg   = (const float*)d_in[6];
  const float* att_src = (const float*)d_in[7];
  const float* att_dst = (const float*)d_in[8];
  const float* bg   = (const float*)d_in[9];
  const float* Wz0  = (const float*)d_in[10];
  const float* bz0  = (const float*)d_in[11];
  const float* Wz1  = (const float*)d_in[12];
  const float* bz1  = (const float*)d_in[13];
  const float* Wr0  = (const float*)d_in[14];
  const float* br0  = (const float*)d_in[15];
  const float* Wr1  = (const float*)d_in[16];
  const float* br1  = (const float*)d_in[17];
  const float* Wh0  = (const float*)d_in[18];
  const float* bh0  = (const float*)d_in[19];
  const float* Wh1  = (const float*)d_in[20];
  const float* bh1  = (const float*)d_in[21];
  const float* Wemb = (const float*)d_in[22];
  const float* Wmlp = (const float*)d_in[23];
  float* out = (float*)d_out;

  char* w = (char*)d_ws;
  float* x  = (float*)(w + 0);                              // 50,331,648 B
  float* ag = (float*)(w + 50331648);                       // 50,331,648 B
  __hip_bfloat16* h = (__hip_bfloat16*)(w + 100663296);     // 25,165,824 B
  float* T  = (float*)(w + 100663296);                      // aliases h (dead after gather)
  __hip_bfloat16* u = (__hip_bfloat16*)(w + 125829120);     // 25,165,824 B
  float* a_s = (float*)(w + 150994944);                     // 524,288 B
  float* a_d = (float*)(w + 151519232);                     // 524,288 B

  hipLaunchKernelGGL(k_embed_mm, dim3(256), dim3(512), 0, stream, embed, We, T);
  hipLaunchKernelGGL(k_gather, dim3(2048), dim3(256), 0, stream, node_ids, T, be, x);
  for (int s = 0; s < 2; ++s) {
    hipLaunchKernelGGL(k_h, dim3(1024), dim3(512), 0, stream,
                       x, Wg, att_src, att_dst, h, a_s, a_d);
    hipLaunchKernelGGL(k_att, dim3(512), dim3(256), 0, stream,
                       src, dst, h, a_s, a_d, bg, ag);
    hipLaunchKernelGGL(k_gates, dim3(512), dim3(512), 0, stream,
                       ag, x, Wr0, br0, Wr1, br1, u);
    hipLaunchKernelGGL(k_fin, dim3(256), dim3(512), 0, stream,
                       ag, u, x, Wz0, bz0, Wz1, bz1, Wh0, bh0, Wh1, bh1);
  }
  hipLaunchKernelGGL(k_readout, dim3(512), dim3(512), 0, stream, x, Wemb, Wmlp, out);
}

// Round 2
// 1634.347 us; speedup vs baseline: 12.0479x; 12.0479x over previous
//
#include <hip/hip_runtime.h>
#include <hip/hip_bf16.h>

#define NNODES 131072
#define LGRAPH 256
#define BGRAPH 512
#define DIN 300
#define DH 96
#define EPG 2048
#define VOCAB 50001
#define NCLS 20
#define NEG 0.2f
#define EMB_ROWS 50048   // VOCAB padded to 128-row tiles
#define EMB_K 320        // 300 padded to 32-multiple

typedef __attribute__((ext_vector_type(4))) float f32x4;
typedef __attribute__((ext_vector_type(8))) short bf16x8;
#define MFMA16(a, b, c) __builtin_amdgcn_mfma_f32_16x16x32_bf16(a, b, c, 0, 0, 0)

__device__ __forceinline__ unsigned short f2b(float f) {
  __hip_bfloat16 h = __float2bfloat16(f);
  return *reinterpret_cast<unsigned short*>(&h);
}
__device__ __forceinline__ float b2f(unsigned short u) {
  __hip_bfloat16 h = *reinterpret_cast<__hip_bfloat16*>(&u);
  return __bfloat162float(h);
}
__device__ __forceinline__ float sigm(float v) { return 1.f / (1.f + __expf(-v)); }
__device__ __forceinline__ unsigned fenc(float f) {
  unsigned u = __float_as_uint(f);
  return (u & 0x80000000u) ? ~u : (u | 0x80000000u);
}
__device__ __forceinline__ float fdec(unsigned u) {
  return __uint_as_float((u & 0x80000000u) ? (u & 0x7fffffffu) : ~u);
}

// ---- weight prep: W[k][c] f32 -> WT[c][k] bf16 (8 DH x DH mats) ; WeT[c][k] padded ----
__global__ void k_prep_w(const float* __restrict__ Wg, const float* __restrict__ Wz0,
                         const float* __restrict__ Wz1, const float* __restrict__ Wr0,
                         const float* __restrict__ Wr1, const float* __restrict__ Wh0,
                         const float* __restrict__ Wh1, const float* __restrict__ Wemb,
                         const float* __restrict__ We,
                         unsigned short* __restrict__ WT, unsigned short* __restrict__ WeT) {
  const int b = blockIdx.x, t = threadIdx.x;
  if (b < 8) {
    const float* src = (b == 0) ? Wg : (b == 1) ? Wz0 : (b == 2) ? Wz1 : (b == 3) ? Wr0
                     : (b == 4) ? Wr1 : (b == 5) ? Wh0 : (b == 6) ? Wh1 : Wemb;
    unsigned short* dst = WT + b * DH * DH;
    for (int i = t; i < DH * DH; i += 256) {
      int c = i / DH, k = i - c * DH;
      dst[i] = f2b(src[k * DH + c]);
    }
  } else {
    for (int i = t; i < DH * EMB_K; i += 256) {
      int c = i / EMB_K, k = i - c * EMB_K;
      WeT[i] = (k < DIN) ? f2b(We[k * DH + c]) : (unsigned short)0;
    }
  }
}

// ---- embed f32 -> padded bf16 ----
__global__ void k_emb_cvt(const float* __restrict__ embed, unsigned short* __restrict__ embB) {
  const int total = EMB_ROWS * EMB_K;
  for (int i = blockIdx.x * blockDim.x + threadIdx.x; i < total;
       i += gridDim.x * blockDim.x) {
    int row = i / EMB_K, k = i - row * EMB_K;
    embB[i] = (row < VOCAB && k < DIN) ? f2b(embed[row * DIN + k]) : (unsigned short)0;
  }
}

// ---- T = embB @ We  (MFMA, M-tile 128) ----
__global__ void k_emb_mm(const unsigned short* __restrict__ embB,
                         const unsigned short* __restrict__ WeT, float* __restrict__ T) {
  const int t = threadIdx.x, w = t >> 6, l = t & 63, li = l & 15, lh = l >> 4;
  const int wbase = blockIdx.x * 128 + w * 32;
  f32x4 acc[2][6];
  #pragma unroll
  for (int rt = 0; rt < 2; rt++)
    #pragma unroll
    for (int ct = 0; ct < 6; ct++) acc[rt][ct] = (f32x4)0.f;
  for (int ks = 0; ks < 10; ++ks) {
    const int ko = lh * 8 + ks * 32;
    bf16x8 aA0 = *(const bf16x8*)&embB[(wbase + li) * EMB_K + ko];
    bf16x8 aA1 = *(const bf16x8*)&embB[(wbase + 16 + li) * EMB_K + ko];
    #pragma unroll
    for (int ct = 0; ct < 6; ct++) {
      bf16x8 bB = *(const bf16x8*)&WeT[(ct * 16 + li) * EMB_K + ko];
      acc[0][ct] = MFMA16(aA0, bB, acc[0][ct]);
      acc[1][ct] = MFMA16(aA1, bB, acc[1][ct]);
    }
  }
  #pragma unroll
  for (int rt = 0; rt < 2; rt++)
    #pragma unroll
    for (int ct = 0; ct < 6; ct++)
      #pragma unroll
      for (int r = 0; r < 4; r++)
        T[(wbase + rt * 16 + lh * 4 + r) * DH + ct * 16 + li] = acc[rt][ct][r];
}

// ---- x = tanh(T[ids] + be), dual f32 + bf16 output ----
__global__ void k_gather(const int* __restrict__ ids, const float* __restrict__ T,
                         const float* __restrict__ be, float* __restrict__ xf,
                         unsigned short* __restrict__ xb) {
  const int total = NNODES * (DH / 4);
  for (int i = blockIdx.x * blockDim.x + threadIdx.x; i < total;
       i += gridDim.x * blockDim.x) {
    int n = i / (DH / 4);
    int q = i - n * (DH / 4);
    float4 v = ((const float4*)(T + ids[n] * DH))[q];
    float4 b = ((const float4*)be)[q];
    float4 o;
    o.x = tanhf(v.x + b.x); o.y = tanhf(v.y + b.y);
    o.z = tanhf(v.z + b.z); o.w = tanhf(v.w + b.w);
    ((float4*)xf)[i] = o;
    ushort4 u4;
    u4.x = f2b(o.x); u4.y = f2b(o.y); u4.z = f2b(o.z); u4.w = f2b(o.w);
    *(ushort4*)&xb[i * 4] = u4;
  }
}

// ---- h = xb @ Wg (bf16 out) + a_s/a_d row reductions (MFMA, M-tile 128) ----
__global__ void k_h(const unsigned short* __restrict__ xb,
                    const unsigned short* __restrict__ WgT,
                    const float* __restrict__ att_s, const float* __restrict__ att_d,
                    unsigned short* __restrict__ h, float* __restrict__ a_s,
                    float* __restrict__ a_d) {
  const int t = threadIdx.x, w = t >> 6, l = t & 63, li = l & 15, lh = l >> 4;
  const int wbase = blockIdx.x * 128 + w * 32;
  f32x4 acc[2][6];
  #pragma unroll
  for (int rt = 0; rt < 2; rt++)
    #pragma unroll
    for (int ct = 0; ct < 6; ct++) acc[rt][ct] = (f32x4)0.f;
  #pragma unroll
  for (int ks = 0; ks < 3; ++ks) {
    const int ko = lh * 8 + ks * 32;
    bf16x8 aA0 = *(const bf16x8*)&xb[(wbase + li) * DH + ko];
    bf16x8 aA1 = *(const bf16x8*)&xb[(wbase + 16 + li) * DH + ko];
    #pragma unroll
    for (int ct = 0; ct < 6; ct++) {
      bf16x8 bB = *(const bf16x8*)&WgT[(ct * 16 + li) * DH + ko];
      acc[0][ct] = MFMA16(aA0, bB, acc[0][ct]);
      acc[1][ct] = MFMA16(aA1, bB, acc[1][ct]);
    }
  }
  float ps[2][4] = {}, pd[2][4] = {};
  #pragma unroll
  for (int rt = 0; rt < 2; rt++)
    #pragma unroll
    for (int ct = 0; ct < 6; ct++) {
      const int col = ct * 16 + li;
      const float as_ = att_s[col], ad_ = att_d[col];
      #pragma unroll
      for (int r = 0; r < 4; r++) {
        float v = acc[rt][ct][r];
        h[(wbase + rt * 16 + lh * 4 + r) * DH + col] = f2b(v);
        ps[rt][r] += v * as_;
        pd[rt][r] += v * ad_;
      }
    }
  #pragma unroll
  for (int rt = 0; rt < 2; rt++)
    #pragma unroll
    for (int r = 0; r < 4; r++) {
      float s = ps[rt][r], d = pd[rt][r];
      #pragma unroll
      for (int m = 1; m < 16; m <<= 1) { s += __shfl_xor(s, m); d += __shfl_xor(d, m); }
      if (li == 0) {
        const int row = wbase + rt * 16 + lh * 4 + r;
        a_s[row] = s;
        a_d[row] = d;
      }
    }
}

// ---- per-graph GAT softmax + aggregation (bf16 a out) ----
__global__ __launch_bounds__(256) void k_att(
    const int* __restrict__ src, const int* __restrict__ dst,
    const unsigned short* __restrict__ h, const float* __restrict__ a_sg,
    const float* __restrict__ a_dg, const float* __restrict__ bg,
    unsigned short* __restrict__ aout) {
  __shared__ float s_as[LGRAPH], s_ad[LGRAPH], s_den[LGRAPH];
  __shared__ unsigned s_m[LGRAPH];
  __shared__ float s_e[EPG];
  __shared__ unsigned char s_sl[EPG], s_dl[EPG];
  __shared__ float s_bg[DH];
  __shared__ float s_a[LGRAPH * DH];   // 96 KB
  const int g = blockIdx.x, t = threadIdx.x;
  const int nb = g * LGRAPH;
  {
    float as = a_sg[nb + t], ad = a_dg[nb + t];
    s_as[t] = as; s_ad[t] = ad;
    float se = as + ad; se = se > 0.f ? se : NEG * se;
    s_m[t] = fenc(se);
  }
  if (t < DH) s_bg[t] = bg[t];
  for (int e = t; e < EPG; e += 256) {
    s_sl[e] = (unsigned char)(src[g * EPG + e] - nb);
    s_dl[e] = (unsigned char)(dst[g * EPG + e] - nb);
  }
  __syncthreads();
  for (int e = t; e < EPG; e += 256) {
    int sl = s_sl[e], dl = s_dl[e];
    float ee = s_as[sl] + s_ad[dl];
    ee = ee > 0.f ? ee : NEG * ee;
    s_e[e] = ee;
    atomicMax(&s_m[dl], fenc(ee));
  }
  __syncthreads();
  {
    float m = fdec(s_m[t]);
    float se = s_as[t] + s_ad[t]; se = se > 0.f ? se : NEG * se;
    s_den[t] = __expf(se - m);
    s_m[t] = __float_as_uint(m);
  }
  __syncthreads();
  for (int e = t; e < EPG; e += 256) {
    int dl = s_dl[e];
    float ex = __expf(s_e[e] - __uint_as_float(s_m[dl]));
    s_e[e] = ex;
    atomicAdd(&s_den[dl], ex);
  }
  __syncthreads();
  {
    float m = __uint_as_float(s_m[t]);
    float se = s_as[t] + s_ad[t]; se = se > 0.f ? se : NEG * se;
    float sa = __expf(se - m) / s_den[t];
    __syncthreads();
    s_as[t] = sa;
  }
  for (int e = t; e < EPG; e += 256) s_e[e] /= s_den[s_dl[e]];
  __syncthreads();
  const int wv = t >> 6, ln = t & 63;
  for (int i = wv; i < LGRAPH; i += 4) {
    float al = s_as[i];
    const unsigned short* hp = &h[(nb + i) * DH];
    float* ap = &s_a[i * DH];
    ap[ln] = al * b2f(hp[ln]);
    if (ln < DH - 64) ap[64 + ln] = al * b2f(hp[64 + ln]);
  }
  __syncthreads();
  for (int e = wv; e < EPG; e += 4) {
    float al = s_e[e];
    int dl = s_dl[e], sl = s_sl[e];
    const unsigned short* hp = &h[(nb + sl) * DH];
    float* ap = &s_a[dl * DH];
    atomicAdd(&ap[ln], al * b2f(hp[ln]));
    if (ln < DH - 64) atomicAdd(&ap[64 + ln], al * b2f(hp[64 + ln]));
  }
  __syncthreads();
  for (int i = wv; i < LGRAPH; i += 4) {
    const float* ap = &s_a[i * DH];
    unsigned short* og = &aout[(nb + i) * DH];
    og[ln] = f2b(ap[ln] + s_bg[ln]);
    if (ln < DH - 64) og[64 + ln] = f2b(ap[64 + ln] + s_bg[64 + ln]);
  }
}

// ---- fused GRU: r -> u=x*r -> z,hh -> x update (MFMA, M-tile 64) ----
__global__ void k_gru(const unsigned short* __restrict__ ab,
                      unsigned short* __restrict__ xb, float* __restrict__ xf,
                      const unsigned short* __restrict__ Wz0T, const unsigned short* __restrict__ Wz1T,
                      const unsigned short* __restrict__ Wr0T, const unsigned short* __restrict__ Wr1T,
                      const unsigned short* __restrict__ Wh0T, const unsigned short* __restrict__ Wh1T,
                      const float* __restrict__ bz0, const float* __restrict__ bz1,
                      const float* __restrict__ br0, const float* __restrict__ br1,
                      const float* __restrict__ bh0, const float* __restrict__ bh1) {
  __shared__ unsigned short U[64 * DH];
  const int t = threadIdx.x, w = t >> 6, l = t & 63, li = l & 15, lh = l >> 4;
  const int nb = blockIdx.x * 64 + w * 16;
  bf16x8 aA[3], aX[3];
  #pragma unroll
  for (int ks = 0; ks < 3; ks++) {
    const int ko = lh * 8 + ks * 32;
    aA[ks] = *(const bf16x8*)&ab[(nb + li) * DH + ko];
    aX[ks] = *(const bf16x8*)&xb[(nb + li) * DH + ko];
  }
  // r gate
  f32x4 accR[6];
  #pragma unroll
  for (int ct = 0; ct < 6; ct++) accR[ct] = (f32x4)0.f;
  #pragma unroll
  for (int ks = 0; ks < 3; ks++) {
    const int ko = lh * 8 + ks * 32;
    #pragma unroll
    for (int ct = 0; ct < 6; ct++) {
      bf16x8 b0 = *(const bf16x8*)&Wr0T[(ct * 16 + li) * DH + ko];
      bf16x8 b1 = *(const bf16x8*)&Wr1T[(ct * 16 + li) * DH + ko];
      accR[ct] = MFMA16(aA[ks], b0, accR[ct]);
      accR[ct] = MFMA16(aX[ks], b1, accR[ct]);
    }
  }
  // u = x * sigmoid(r) -> LDS (bf16)
  f32x4 xo[6];
  #pragma unroll
  for (int ct = 0; ct < 6; ct++) {
    const int col = ct * 16 + li;
    const float rb = br0[col] + br1[col];
    #pragma unroll
    for (int r = 0; r < 4; r++) {
      const int row = nb + lh * 4 + r;
      float xv = xf[row * DH + col];
      xo[ct][r] = xv;
      float rv = sigm(accR[ct][r] + rb);
      U[(w * 16 + lh * 4 + r) * DH + col] = f2b(xv * rv);
    }
  }
  __syncthreads();
  // z gate
  f32x4 accZ[6];
  #pragma unroll
  for (int ct = 0; ct < 6; ct++) accZ[ct] = (f32x4)0.f;
  #pragma unroll
  for (int ks = 0; ks < 3; ks++) {
    const int ko = lh * 8 + ks * 32;
    #pragma unroll
    for (int ct = 0; ct < 6; ct++) {
      bf16x8 b0 = *(const bf16x8*)&Wz0T[(ct * 16 + li) * DH + ko];
      bf16x8 b1 = *(const bf16x8*)&Wz1T[(ct * 16 + li) * DH + ko];
      accZ[ct] = MFMA16(aA[ks], b0, accZ[ct]);
      accZ[ct] = MFMA16(aX[ks], b1, accZ[ct]);
    }
  }
  // hh
  bf16x8 aU[3];
  #pragma unroll
  for (int ks = 0; ks < 3; ks++)
    aU[ks] = *(const bf16x8*)&U[(w * 16 + li) * DH + lh * 8 + ks * 32];
  f32x4 accH[6];
  #pragma unroll
  for (int ct = 0; ct < 6; ct++) accH[ct] = (f32x4)0.f;
  #pragma unroll
  for (int ks = 0; ks < 3; ks++) {
    const int ko = lh * 8 + ks * 32;
    #pragma unroll
    for (int ct = 0; ct < 6; ct++) {
      bf16x8 b0 = *(const bf16x8*)&Wh0T[(ct * 16 + li) * DH + ko];
      bf16x8 b1 = *(const bf16x8*)&Wh1T[(ct * 16 + li) * DH + ko];
      accH[ct] = MFMA16(aA[ks], b0, accH[ct]);
      accH[ct] = MFMA16(aU[ks], b1, accH[ct]);
    }
  }
  // epilogue
  #pragma unroll
  for (int ct = 0; ct < 6; ct++) {
    const int col = ct * 16 + li;
    const float zb = bz0[col] + bz1[col];
    const float hb = bh0[col] + bh1[col];
    #pragma unroll
    for (int r = 0; r < 4; r++) {
      const int row = nb + lh * 4 + r;
      float z = sigm(accZ[ct][r] + zb);
      float hh = tanhf(accH[ct][r] + hb);
      float xn = hh * z + xo[ct][r] * (1.f - z);
      xf[row * DH + col] = xn;
      xb[row * DH + col] = f2b(xn);
    }
  }
}

// ---- readout: y = tanh(xb @ Wemb); pool max+mean; out = pooled @ Wmlp ----
__global__ void k_readout(const unsigned short* __restrict__ xb,
                          const unsigned short* __restrict__ WembT,
                          const float* __restrict__ Wmlp, float* __restrict__ out) {
  __shared__ float pmaxs[4][DH], psums[4][DH];
  __shared__ float spool[DH];
  const int g = blockIdx.x, t = threadIdx.x, w = t >> 6, l = t & 63, li = l & 15, lh = l >> 4;
  const int wbase = g * LGRAPH + w * 64;
  f32x4 acc[4][6];
  #pragma unroll
  for (int rt = 0; rt < 4; rt++)
    #pragma unroll
    for (int ct = 0; ct < 6; ct++) acc[rt][ct] = (f32x4)0.f;
  #pragma unroll
  for (int ks = 0; ks < 3; ks++) {
    const int ko = lh * 8 + ks * 32;
    bf16x8 aA[4];
    #pragma unroll
    for (int rt = 0; rt < 4; rt++)
      aA[rt] = *(const bf16x8*)&xb[(wbase + rt * 16 + li) * DH + ko];
    #pragma unroll
    for (int ct = 0; ct < 6; ct++) {
      bf16x8 bB = *(const bf16x8*)&WembT[(ct * 16 + li) * DH + ko];
      #pragma unroll
      for (int rt = 0; rt < 4; rt++) acc[rt][ct] = MFMA16(aA[rt], bB, acc[rt][ct]);
    }
  }
  float pm[6], psu[6];
  #pragma unroll
  for (int ct = 0; ct < 6; ct++) {
    float mx = -1e30f, sm = 0.f;
    #pragma unroll
    for (int rt = 0; rt < 4; rt++)
      #pragma unroll
      for (int r = 0; r < 4; r++) {
        float y = tanhf(acc[rt][ct][r]);
        mx = fmaxf(mx, y);
        sm += y;
      }
    pm[ct] = mx; psu[ct] = sm;
  }
  #pragma unroll
  for (int ct = 0; ct < 6; ct++) {
    pm[ct] = fmaxf(pm[ct], __shfl_xor(pm[ct], 16));
    psu[ct] += __shfl_xor(psu[ct], 16);
    pm[ct] = fmaxf(pm[ct], __shfl_xor(pm[ct], 32));
    psu[ct] += __shfl_xor(psu[ct], 32);
  }
  if (lh == 0) {
    #pragma unroll
    for (int ct = 0; ct < 6; ct++) {
      pmaxs[w][ct * 16 + li] = pm[ct];
      psums[w][ct * 16 + li] = psu[ct];
    }
  }
  __syncthreads();
  if (t < DH) {
    float mx = fmaxf(fmaxf(pmaxs[0][t], pmaxs[1][t]), fmaxf(pmaxs[2][t], pmaxs[3][t]));
    float sm = psums[0][t] + psums[1][t] + psums[2][t] + psums[3][t];
    spool[t] = mx + sm * (1.f / LGRAPH);
  }
  __syncthreads();
  if (t < NCLS) {
    float a = 0.f;
    for (int k = 0; k < DH; ++k) a += spool[k] * Wmlp[k * NCLS + t];
    out[g * NCLS + t] = a;
  }
}

extern "C" void kernel_launch(void* const* d_in, const int* in_sizes, int n_in,
                              void* d_out, int out_size, void* d_ws, size_t ws_size,
                              hipStream_t stream) {
  const int*   node_ids = (const int*)d_in[0];
  const int*   src      = (const int*)d_in[1];
  const int*   dst      = (const int*)d_in[2];
  const float* embed    = (const float*)d_in[3];
  const float* We   = (const float*)d_in[4];
  const float* be   = (const float*)d_in[5];
  const float* Wg   = (const float*)d_in[6];
  const float* att_src = (const float*)d_in[7];
  const float* att_dst = (const float*)d_in[8];
  const float* bg   = (const float*)d_in[9];
  const float* Wz0  = (const float*)d_in[10];
  const float* bz0  = (const float*)d_in[11];
  const float* Wz1  = (const float*)d_in[12];
  const float* bz1  = (const float*)d_in[13];
  const float* Wr0  = (const float*)d_in[14];
  const float* br0  = (const float*)d_in[15];
  const float* Wr1  = (const float*)d_in[16];
  const float* br1  = (const float*)d_in[17];
  const float* Wh0  = (const float*)d_in[18];
  const float* bh0  = (const float*)d_in[19];
  const float* Wh1  = (const float*)d_in[20];
  const float* bh1  = (const float*)d_in[21];
  const float* Wemb = (const float*)d_in[22];
  const float* Wmlp = (const float*)d_in[23];
  float* out = (float*)d_out;

  char* w_ = (char*)d_ws;
  float*          xf   = (float*)(w_ + 0);                    // 50,331,648 B
  unsigned short* xb   = (unsigned short*)(w_ + 50331648);    // 25,165,824 B
  unsigned short* ab   = (unsigned short*)(w_ + 75497472);    // 25,165,824 B
  unsigned short* h    = (unsigned short*)(w_ + 100663296);   // 25,165,824 B
  float*          T    = (float*)(w_ + 125829120);            // 19,218,432 B
  float*          a_s  = (float*)(w_ + 145047552);            // 524,288 B
  float*          a_d  = (float*)(w_ + 145571840);            // 524,288 B
  unsigned short* WT   = (unsigned short*)(w_ + 146096128);   // 147,456 B
  unsigned short* WeT  = (unsigned short*)(w_ + 146243584);   // 61,440 B
  unsigned short* embB = (unsigned short*)(w_ + 0);           // alias xf (dead before xf write)

  unsigned short* WgT  = WT + 0 * DH * DH;
  unsigned short* Wz0T = WT + 1 * DH * DH;
  unsigned short* Wz1T = WT + 2 * DH * DH;
  unsigned short* Wr0T = WT + 3 * DH * DH;
  unsigned short* Wr1T = WT + 4 * DH * DH;
  unsigned short* Wh0T = WT + 5 * DH * DH;
  unsigned short* Wh1T = WT + 6 * DH * DH;
  unsigned short* WembT= WT + 7 * DH * DH;

  hipLaunchKernelGGL(k_prep_w, dim3(9), dim3(256), 0, stream,
                     Wg, Wz0, Wz1, Wr0, Wr1, Wh0, Wh1, Wemb, We, WT, WeT);
  hipLaunchKernelGGL(k_emb_cvt, dim3(4096), dim3(256), 0, stream, embed, embB);
  hipLaunchKernelGGL(k_emb_mm, dim3(EMB_ROWS / 128), dim3(256), 0, stream, embB, WeT, T);
  hipLaunchKernelGGL(k_gather, dim3(2048), dim3(256), 0, stream, node_ids, T, be, xf, xb);
  for (int s = 0; s < 2; ++s) {
    hipLaunchKernelGGL(k_h, dim3(NNODES / 128), dim3(256), 0, stream,
                       xb, WgT, att_src, att_dst, h, a_s, a_d);
    hipLaunchKernelGGL(k_att, dim3(BGRAPH), dim3(256), 0, stream,
                       src, dst, h, a_s, a_d, bg, ab);
    hipLaunchKernelGGL(k_gru, dim3(NNODES / 64), dim3(256), 0, stream,
                       ab, xb, xf, Wz0T, Wz1T, Wr0T, Wr1T, Wh0T, Wh1T,
                       bz0, bz1, br0, br1, bh0, bh1);
  }
  hipLaunchKernelGGL(k_readout, dim3(BGRAPH), dim3(256), 0, stream, xb, WembT, Wmlp, out);
}

// Round 3
// 485.589 us; speedup vs baseline: 40.5497x; 3.3657x over previous
//
#include <hip/hip_runtime.h>
#include <hip/hip_bf16.h>

#define NNODES 131072
#define LGRAPH 256
#define BGRAPH 512
#define DIN 300
#define DH 96
#define EPG 2048
#define VOCAB 50001
#define NCLS 20
#define NEG 0.2f
#define EMB_ROWS 50048   // VOCAB padded to 128-row tiles
#define EMB_K 320        // 300 padded to 32-multiple
#define HTS 264          // padded LDS stride (halfs) for transposed tiles

typedef __attribute__((ext_vector_type(4))) float f32x4;
typedef __attribute__((ext_vector_type(8))) short bf16x8;
#define MFMA16(a, b, c) __builtin_amdgcn_mfma_f32_16x16x32_bf16(a, b, c, 0, 0, 0)

__device__ __forceinline__ unsigned short f2b(float f) {
  __hip_bfloat16 h = __float2bfloat16(f);
  return *reinterpret_cast<unsigned short*>(&h);
}
__device__ __forceinline__ float b2f(unsigned short u) {
  __hip_bfloat16 h = *reinterpret_cast<__hip_bfloat16*>(&u);
  return __bfloat162float(h);
}
__device__ __forceinline__ float sigm(float v) { return 1.f / (1.f + __expf(-v)); }
__device__ __forceinline__ unsigned fenc(float f) {
  unsigned u = __float_as_uint(f);
  return (u & 0x80000000u) ? ~u : (u | 0x80000000u);
}
__device__ __forceinline__ float fdec(unsigned u) {
  return __uint_as_float((u & 0x80000000u) ? (u & 0x7fffffffu) : ~u);
}

// ---- weight prep: W[k][c] f32 -> WT[c][k] bf16 (8 DH x DH mats) ; WeT[c][k] padded ----
__global__ void k_prep_w(const float* __restrict__ Wg, const float* __restrict__ Wz0,
                         const float* __restrict__ Wz1, const float* __restrict__ Wr0,
                         const float* __restrict__ Wr1, const float* __restrict__ Wh0,
                         const float* __restrict__ Wh1, const float* __restrict__ Wemb,
                         const float* __restrict__ We,
                         unsigned short* __restrict__ WT, unsigned short* __restrict__ WeT) {
  const int b = blockIdx.x, t = threadIdx.x;
  if (b < 8) {
    const float* src = (b == 0) ? Wg : (b == 1) ? Wz0 : (b == 2) ? Wz1 : (b == 3) ? Wr0
                     : (b == 4) ? Wr1 : (b == 5) ? Wh0 : (b == 6) ? Wh1 : Wemb;
    unsigned short* dst = WT + b * DH * DH;
    for (int i = t; i < DH * DH; i += 256) {
      int c = i / DH, k = i - c * DH;
      dst[i] = f2b(src[k * DH + c]);
    }
  } else {
    for (int i = t; i < DH * EMB_K; i += 256) {
      int c = i / EMB_K, k = i - c * EMB_K;
      WeT[i] = (k < DIN) ? f2b(We[k * DH + c]) : (unsigned short)0;
    }
  }
}

// ---- embed f32 -> padded bf16 ----
__global__ void k_emb_cvt(const float* __restrict__ embed, unsigned short* __restrict__ embB) {
  const int total = EMB_ROWS * EMB_K;
  for (int i = blockIdx.x * blockDim.x + threadIdx.x; i < total;
       i += gridDim.x * blockDim.x) {
    int row = i / EMB_K, k = i - row * EMB_K;
    embB[i] = (row < VOCAB && k < DIN) ? f2b(embed[row * DIN + k]) : (unsigned short)0;
  }
}

// ---- T = embB @ We  (MFMA, M-tile 128) ----
__global__ void k_emb_mm(const unsigned short* __restrict__ embB,
                         const unsigned short* __restrict__ WeT, float* __restrict__ T) {
  const int t = threadIdx.x, w = t >> 6, l = t & 63, li = l & 15, lh = l >> 4;
  const int wbase = blockIdx.x * 128 + w * 32;
  f32x4 acc[2][6];
  #pragma unroll
  for (int rt = 0; rt < 2; rt++)
    #pragma unroll
    for (int ct = 0; ct < 6; ct++) acc[rt][ct] = (f32x4)0.f;
  for (int ks = 0; ks < 10; ++ks) {
    const int ko = lh * 8 + ks * 32;
    bf16x8 aA0 = *(const bf16x8*)&embB[(wbase + li) * EMB_K + ko];
    bf16x8 aA1 = *(const bf16x8*)&embB[(wbase + 16 + li) * EMB_K + ko];
    #pragma unroll
    for (int ct = 0; ct < 6; ct++) {
      bf16x8 bB = *(const bf16x8*)&WeT[(ct * 16 + li) * EMB_K + ko];
      acc[0][ct] = MFMA16(aA0, bB, acc[0][ct]);
      acc[1][ct] = MFMA16(aA1, bB, acc[1][ct]);
    }
  }
  #pragma unroll
  for (int rt = 0; rt < 2; rt++)
    #pragma unroll
    for (int ct = 0; ct < 6; ct++)
      #pragma unroll
      for (int r = 0; r < 4; r++)
        T[(wbase + rt * 16 + lh * 4 + r) * DH + ct * 16 + li] = acc[rt][ct][r];
}

// ---- x = tanh(T[ids] + be), dual f32 + bf16 output ----
__global__ void k_gather(const int* __restrict__ ids, const float* __restrict__ T,
                         const float* __restrict__ be, float* __restrict__ xf,
                         unsigned short* __restrict__ xb) {
  const int total = NNODES * (DH / 4);
  for (int i = blockIdx.x * blockDim.x + threadIdx.x; i < total;
       i += gridDim.x * blockDim.x) {
    int n = i / (DH / 4);
    int q = i - n * (DH / 4);
    float4 v = ((const float4*)(T + ids[n] * DH))[q];
    float4 b = ((const float4*)be)[q];
    float4 o;
    o.x = tanhf(v.x + b.x); o.y = tanhf(v.y + b.y);
    o.z = tanhf(v.z + b.z); o.w = tanhf(v.w + b.w);
    ((float4*)xf)[i] = o;
    ushort4 u4;
    u4.x = f2b(o.x); u4.y = f2b(o.y); u4.z = f2b(o.z); u4.w = f2b(o.w);
    *(ushort4*)&xb[i * 4] = u4;
  }
}

// ---- h = xb @ Wg (bf16 out) + a_s/a_d row reductions (MFMA, M-tile 128) ----
__global__ void k_h(const unsigned short* __restrict__ xb,
                    const unsigned short* __restrict__ WgT,
                    const float* __restrict__ att_s, const float* __restrict__ att_d,
                    unsigned short* __restrict__ h, float* __restrict__ a_s,
                    float* __restrict__ a_d) {
  const int t = threadIdx.x, w = t >> 6, l = t & 63, li = l & 15, lh = l >> 4;
  const int wbase = blockIdx.x * 128 + w * 32;
  f32x4 acc[2][6];
  #pragma unroll
  for (int rt = 0; rt < 2; rt++)
    #pragma unroll
    for (int ct = 0; ct < 6; ct++) acc[rt][ct] = (f32x4)0.f;
  #pragma unroll
  for (int ks = 0; ks < 3; ++ks) {
    const int ko = lh * 8 + ks * 32;
    bf16x8 aA0 = *(const bf16x8*)&xb[(wbase + li) * DH + ko];
    bf16x8 aA1 = *(const bf16x8*)&xb[(wbase + 16 + li) * DH + ko];
    #pragma unroll
    for (int ct = 0; ct < 6; ct++) {
      bf16x8 bB = *(const bf16x8*)&WgT[(ct * 16 + li) * DH + ko];
      acc[0][ct] = MFMA16(aA0, bB, acc[0][ct]);
      acc[1][ct] = MFMA16(aA1, bB, acc[1][ct]);
    }
  }
  float ps[2][4] = {}, pd[2][4] = {};
  #pragma unroll
  for (int rt = 0; rt < 2; rt++)
    #pragma unroll
    for (int ct = 0; ct < 6; ct++) {
      const int col = ct * 16 + li;
      const float as_ = att_s[col], ad_ = att_d[col];
      #pragma unroll
      for (int r = 0; r < 4; r++) {
        float v = acc[rt][ct][r];
        h[(wbase + rt * 16 + lh * 4 + r) * DH + col] = f2b(v);
        ps[rt][r] += v * as_;
        pd[rt][r] += v * ad_;
      }
    }
  #pragma unroll
  for (int rt = 0; rt < 2; rt++)
    #pragma unroll
    for (int r = 0; r < 4; r++) {
      float s = ps[rt][r], d = pd[rt][r];
      #pragma unroll
      for (int m = 1; m < 16; m <<= 1) { s += __shfl_xor(s, m); d += __shfl_xor(d, m); }
      if (li == 0) {
        const int row = wbase + rt * 16 + lh * 4 + r;
        a_s[row] = s;
        a_d[row] = d;
      }
    }
}

// ---- per-graph GAT: softmax as dense P (unnormalized exp), a = inv_den*(P@h)+bg via MFMA ----
__global__ __launch_bounds__(512) void k_att(
    const int* __restrict__ src, const int* __restrict__ dst,
    const unsigned short* __restrict__ h, const float* __restrict__ a_sg,
    const float* __restrict__ a_dg, const float* __restrict__ bg,
    unsigned short* __restrict__ aout) {
  __shared__ __align__(16) unsigned short hT[DH * HTS];        // 50688 B, transposed h
  __shared__ __align__(16) float Pf[64 * LGRAPH];              // 65536 B (aliased by bf16 Pb)
  __shared__ float s_e[EPG];                                   // 8192 B: logits -> exp
  __shared__ unsigned char s_sl[EPG], s_dl[EPG];               // 4096 B
  __shared__ float s_as[LGRAPH], s_ad[LGRAPH];                 // 2048 B
  __shared__ float s_den[LGRAPH], s_inv[LGRAPH], s_selfex[LGRAPH];
  __shared__ unsigned s_m[LGRAPH];
  __shared__ float s_bg[DH];
  const int g = blockIdx.x, t = threadIdx.x;
  const int nb = g * LGRAPH;
  const int w = t >> 6, l = t & 63, li = l & 15, lh = l >> 4;

  // ---- phase 0: loads ----
  if (t < LGRAPH) {
    float as = a_sg[nb + t], ad = a_dg[nb + t];
    s_as[t] = as; s_ad[t] = ad;
    float se = as + ad; se = se > 0.f ? se : NEG * se;  // self-loop logit
    s_selfex[t] = se;
    s_m[t] = fenc(se);
  }
  if (t < DH) s_bg[t] = bg[t];
  for (int e = t; e < EPG; e += 512) {
    s_sl[e] = (unsigned char)(src[g * EPG + e] - nb);
    s_dl[e] = (unsigned char)(dst[g * EPG + e] - nb);
  }
  // stage h transposed: hT[col][row], padded stride
  for (int idx = t; idx < LGRAPH * (DH / 2); idx += 512) {
    int row = idx / (DH / 2), cp = idx - row * (DH / 2);
    unsigned v = ((const unsigned*)&h[(nb + row) * DH])[cp];
    hT[(2 * cp) * HTS + row] = (unsigned short)(v & 0xffff);
    hT[(2 * cp + 1) * HTS + row] = (unsigned short)(v >> 16);
  }
  __syncthreads();
  // ---- phase 1: edge logits + segment max ----
  for (int e = t; e < EPG; e += 512) {
    float ee = s_as[s_sl[e]] + s_ad[s_dl[e]];
    ee = ee > 0.f ? ee : NEG * ee;
    s_e[e] = ee;
    atomicMax(&s_m[s_dl[e]], fenc(ee));
  }
  __syncthreads();
  // ---- phase 2a: self exp, den init, stash m as float bits ----
  if (t < LGRAPH) {
    float m = fdec(s_m[t]);
    float sx = __expf(s_selfex[t] - m);
    s_selfex[t] = sx;
    s_den[t] = sx;
    s_m[t] = __float_as_uint(m);
  }
  __syncthreads();
  // ---- phase 2b: edge exp + den accumulate ----
  for (int e = t; e < EPG; e += 512) {
    int dl = s_dl[e];
    float ex = __expf(s_e[e] - __uint_as_float(s_m[dl]));
    s_e[e] = ex;
    atomicAdd(&s_den[dl], ex);
  }
  __syncthreads();
  if (t < LGRAPH) s_inv[t] = 1.f / s_den[t];
  __syncthreads();

  // ---- tiles of 64 dst rows: build P, pack bf16, MFMA ----
  unsigned short* Pb = (unsigned short*)Pf;   // packed [64][HTS]
  const int rb = w >> 1, ct0 = (w & 1) * 3;   // wave's output unit set
  for (int tb = 0; tb < 4; ++tb) {
    const int base = tb * 64;
    // zero
    for (int i = t; i < 64 * LGRAPH / 4; i += 512) ((float4*)Pf)[i] = make_float4(0.f, 0.f, 0.f, 0.f);
    __syncthreads();
    // scatter edges + self
    for (int e = t; e < EPG; e += 512) {
      unsigned r = (unsigned)(s_dl[e] - base);
      if (r < 64u) atomicAdd(&Pf[r * LGRAPH + s_sl[e]], s_e[e]);
    }
    if (t < 64) {
      int d = base + t;
      atomicAdd(&Pf[t * LGRAPH + d], s_selfex[d]);
    }
    __syncthreads();
    // pack f32 -> bf16 in place (read all to regs, sync, write padded)
    unsigned pk[16];
    #pragma unroll
    for (int i = 0; i < 16; ++i) {
      int wd = t + 512 * i;
      float2 v = *(const float2*)&Pf[2 * wd];
      pk[i] = (unsigned)f2b(v.x) | ((unsigned)f2b(v.y) << 16);
    }
    __syncthreads();
    #pragma unroll
    for (int i = 0; i < 16; ++i) {
      int wd = t + 512 * i;
      int r = wd >> 7, c2 = wd & 127;
      ((unsigned*)Pb)[r * (HTS / 2) + c2] = pk[i];
    }
    __syncthreads();
    // MFMA: 64 x 256 @ 256 x 96 ; wave does rows rb*16.. , cols ct0*16..(+3 tiles)
    f32x4 acc0 = (f32x4)0.f, acc1 = (f32x4)0.f, acc2 = (f32x4)0.f;
    #pragma unroll
    for (int ks = 0; ks < 8; ++ks) {
      const int ko = ks * 32 + lh * 8;
      bf16x8 aF = *(const bf16x8*)&Pb[(rb * 16 + li) * HTS + ko];
      bf16x8 b0 = *(const bf16x8*)&hT[(ct0 * 16 + li) * HTS + ko];
      bf16x8 b1 = *(const bf16x8*)&hT[((ct0 + 1) * 16 + li) * HTS + ko];
      bf16x8 b2 = *(const bf16x8*)&hT[((ct0 + 2) * 16 + li) * HTS + ko];
      acc0 = MFMA16(aF, b0, acc0);
      acc1 = MFMA16(aF, b1, acc1);
      acc2 = MFMA16(aF, b2, acc2);
    }
    // epilogue: a = acc * inv_den[row] + bg[col]
    #pragma unroll
    for (int r = 0; r < 4; ++r) {
      const int d = base + rb * 16 + lh * 4 + r;
      const float iv = s_inv[d];
      unsigned short* op = &aout[(nb + d) * DH];
      op[ct0 * 16 + li] = f2b(acc0[r] * iv + s_bg[ct0 * 16 + li]);
      op[(ct0 + 1) * 16 + li] = f2b(acc1[r] * iv + s_bg[(ct0 + 1) * 16 + li]);
      op[(ct0 + 2) * 16 + li] = f2b(acc2[r] * iv + s_bg[(ct0 + 2) * 16 + li]);
    }
    __syncthreads();   // Pb (=Pf) must be fully read before next tile zeroes it
  }
}

// ---- fused GRU: r -> u=x*r -> z,hh -> x update (MFMA, M-tile 64) ----
__global__ void k_gru(const unsigned short* __restrict__ ab,
                      unsigned short* __restrict__ xb, float* __restrict__ xf,
                      const unsigned short* __restrict__ Wz0T, const unsigned short* __restrict__ Wz1T,
                      const unsigned short* __restrict__ Wr0T, const unsigned short* __restrict__ Wr1T,
                      const unsigned short* __restrict__ Wh0T, const unsigned short* __restrict__ Wh1T,
                      const float* __restrict__ bz0, const float* __restrict__ bz1,
                      const float* __restrict__ br0, const float* __restrict__ br1,
                      const float* __restrict__ bh0, const float* __restrict__ bh1) {
  __shared__ unsigned short U[64 * DH];
  const int t = threadIdx.x, w = t >> 6, l = t & 63, li = l & 15, lh = l >> 4;
  const int nb = blockIdx.x * 64 + w * 16;
  bf16x8 aA[3], aX[3];
  #pragma unroll
  for (int ks = 0; ks < 3; ks++) {
    const int ko = lh * 8 + ks * 32;
    aA[ks] = *(const bf16x8*)&ab[(nb + li) * DH + ko];
    aX[ks] = *(const bf16x8*)&xb[(nb + li) * DH + ko];
  }
  // r gate
  f32x4 accR[6];
  #pragma unroll
  for (int ct = 0; ct < 6; ct++) accR[ct] = (f32x4)0.f;
  #pragma unroll
  for (int ks = 0; ks < 3; ks++) {
    const int ko = lh * 8 + ks * 32;
    #pragma unroll
    for (int ct = 0; ct < 6; ct++) {
      bf16x8 b0 = *(const bf16x8*)&Wr0T[(ct * 16 + li) * DH + ko];
      bf16x8 b1 = *(const bf16x8*)&Wr1T[(ct * 16 + li) * DH + ko];
      accR[ct] = MFMA16(aA[ks], b0, accR[ct]);
      accR[ct] = MFMA16(aX[ks], b1, accR[ct]);
    }
  }
  // u = x * sigmoid(r) -> LDS (bf16)
  f32x4 xo[6];
  #pragma unroll
  for (int ct = 0; ct < 6; ct++) {
    const int col = ct * 16 + li;
    const float rb = br0[col] + br1[col];
    #pragma unroll
    for (int r = 0; r < 4; r++) {
      const int row = nb + lh * 4 + r;
      float xv = xf[row * DH + col];
      xo[ct][r] = xv;
      float rv = sigm(accR[ct][r] + rb);
      U[(w * 16 + lh * 4 + r) * DH + col] = f2b(xv * rv);
    }
  }
  __syncthreads();
  // z gate
  f32x4 accZ[6];
  #pragma unroll
  for (int ct = 0; ct < 6; ct++) accZ[ct] = (f32x4)0.f;
  #pragma unroll
  for (int ks = 0; ks < 3; ks++) {
    const int ko = lh * 8 + ks * 32;
    #pragma unroll
    for (int ct = 0; ct < 6; ct++) {
      bf16x8 b0 = *(const bf16x8*)&Wz0T[(ct * 16 + li) * DH + ko];
      bf16x8 b1 = *(const bf16x8*)&Wz1T[(ct * 16 + li) * DH + ko];
      accZ[ct] = MFMA16(aA[ks], b0, accZ[ct]);
      accZ[ct] = MFMA16(aX[ks], b1, accZ[ct]);
    }
  }
  // hh
  bf16x8 aU[3];
  #pragma unroll
  for (int ks = 0; ks < 3; ks++)
    aU[ks] = *(const bf16x8*)&U[(w * 16 + li) * DH + lh * 8 + ks * 32];
  f32x4 accH[6];
  #pragma unroll
  for (int ct = 0; ct < 6; ct++) accH[ct] = (f32x4)0.f;
  #pragma unroll
  for (int ks = 0; ks < 3; ks++) {
    const int ko = lh * 8 + ks * 32;
    #pragma unroll
    for (int ct = 0; ct < 6; ct++) {
      bf16x8 b0 = *(const bf16x8*)&Wh0T[(ct * 16 + li) * DH + ko];
      bf16x8 b1 = *(const bf16x8*)&Wh1T[(ct * 16 + li) * DH + ko];
      accH[ct] = MFMA16(aA[ks], b0, accH[ct]);
      accH[ct] = MFMA16(aU[ks], b1, accH[ct]);
    }
  }
  // epilogue
  #pragma unroll
  for (int ct = 0; ct < 6; ct++) {
    const int col = ct * 16 + li;
    const float zb = bz0[col] + bz1[col];
    const float hb = bh0[col] + bh1[col];
    #pragma unroll
    for (int r = 0; r < 4; r++) {
      const int row = nb + lh * 4 + r;
      float z = sigm(accZ[ct][r] + zb);
      float hh = tanhf(accH[ct][r] + hb);
      float xn = hh * z + xo[ct][r] * (1.f - z);
      xf[row * DH + col] = xn;
      xb[row * DH + col] = f2b(xn);
    }
  }
}

// ---- readout: y = tanh(xb @ Wemb); pool max+mean; out = pooled @ Wmlp ----
__global__ void k_readout(const unsigned short* __restrict__ xb,
                          const unsigned short* __restrict__ WembT,
                          const float* __restrict__ Wmlp, float* __restrict__ out) {
  __shared__ float pmaxs[4][DH], psums[4][DH];
  __shared__ float spool[DH];
  const int g = blockIdx.x, t = threadIdx.x, w = t >> 6, l = t & 63, li = l & 15, lh = l >> 4;
  const int wbase = g * LGRAPH + w * 64;
  f32x4 acc[4][6];
  #pragma unroll
  for (int rt = 0; rt < 4; rt++)
    #pragma unroll
    for (int ct = 0; ct < 6; ct++) acc[rt][ct] = (f32x4)0.f;
  #pragma unroll
  for (int ks = 0; ks < 3; ks++) {
    const int ko = lh * 8 + ks * 32;
    bf16x8 aA[4];
    #pragma unroll
    for (int rt = 0; rt < 4; rt++)
      aA[rt] = *(const bf16x8*)&xb[(wbase + rt * 16 + li) * DH + ko];
    #pragma unroll
    for (int ct = 0; ct < 6; ct++) {
      bf16x8 bB = *(const bf16x8*)&WembT[(ct * 16 + li) * DH + ko];
      #pragma unroll
      for (int rt = 0; rt < 4; rt++) acc[rt][ct] = MFMA16(aA[rt], bB, acc[rt][ct]);
    }
  }
  float pm[6], psu[6];
  #pragma unroll
  for (int ct = 0; ct < 6; ct++) {
    float mx = -1e30f, sm = 0.f;
    #pragma unroll
    for (int rt = 0; rt < 4; rt++)
      #pragma unroll
      for (int r = 0; r < 4; r++) {
        float y = tanhf(acc[rt][ct][r]);
        mx = fmaxf(mx, y);
        sm += y;
      }
    pm[ct] = mx; psu[ct] = sm;
  }
  #pragma unroll
  for (int ct = 0; ct < 6; ct++) {
    pm[ct] = fmaxf(pm[ct], __shfl_xor(pm[ct], 16));
    psu[ct] += __shfl_xor(psu[ct], 16);
    pm[ct] = fmaxf(pm[ct], __shfl_xor(pm[ct], 32));
    psu[ct] += __shfl_xor(psu[ct], 32);
  }
  if (lh == 0) {
    #pragma unroll
    for (int ct = 0; ct < 6; ct++) {
      pmaxs[w][ct * 16 + li] = pm[ct];
      psums[w][ct * 16 + li] = psu[ct];
    }
  }
  __syncthreads();
  if (t < DH) {
    float mx = fmaxf(fmaxf(pmaxs[0][t], pmaxs[1][t]), fmaxf(pmaxs[2][t], pmaxs[3][t]));
    float sm = psums[0][t] + psums[1][t] + psums[2][t] + psums[3][t];
    spool[t] = mx + sm * (1.f / LGRAPH);
  }
  __syncthreads();
  if (t < NCLS) {
    float a = 0.f;
    for (int k = 0; k < DH; ++k) a += spool[k] * Wmlp[k * NCLS + t];
    out[g * NCLS + t] = a;
  }
}

extern "C" void kernel_launch(void* const* d_in, const int* in_sizes, int n_in,
                              void* d_out, int out_size, void* d_ws, size_t ws_size,
                              hipStream_t stream) {
  const int*   node_ids = (const int*)d_in[0];
  const int*   src      = (const int*)d_in[1];
  const int*   dst      = (const int*)d_in[2];
  const float* embed    = (const float*)d_in[3];
  const float* We   = (const float*)d_in[4];
  const float* be   = (const float*)d_in[5];
  const float* Wg   = (const float*)d_in[6];
  const float* att_src = (const float*)d_in[7];
  const float* att_dst = (const float*)d_in[8];
  const float* bg   = (const float*)d_in[9];
  const float* Wz0  = (const float*)d_in[10];
  const float* bz0  = (const float*)d_in[11];
  const float* Wz1  = (const float*)d_in[12];
  const float* bz1  = (const float*)d_in[13];
  const float* Wr0  = (const float*)d_in[14];
  const float* br0  = (const float*)d_in[15];
  const float* Wr1  = (const float*)d_in[16];
  const float* br1  = (const float*)d_in[17];
  const float* Wh0  = (const float*)d_in[18];
  const float* bh0  = (const float*)d_in[19];
  const float* Wh1  = (const float*)d_in[20];
  const float* bh1  = (const float*)d_in[21];
  const float* Wemb = (const float*)d_in[22];
  const float* Wmlp = (const float*)d_in[23];
  float* out = (float*)d_out;

  char* w_ = (char*)d_ws;
  float*          xf   = (float*)(w_ + 0);                    // 50,331,648 B
  unsigned short* xb   = (unsigned short*)(w_ + 50331648);    // 25,165,824 B
  unsigned short* ab   = (unsigned short*)(w_ + 75497472);    // 25,165,824 B
  unsigned short* h    = (unsigned short*)(w_ + 100663296);   // 25,165,824 B
  float*          T    = (float*)(w_ + 125829120);            // 19,218,432 B
  float*          a_s  = (float*)(w_ + 145047552);            // 524,288 B
  float*          a_d  = (float*)(w_ + 145571840);            // 524,288 B
  unsigned short* WT   = (unsigned short*)(w_ + 146096128);   // 147,456 B
  unsigned short* WeT  = (unsigned short*)(w_ + 146243584);   // 61,440 B
  unsigned short* embB = (unsigned short*)(w_ + 0);           // alias xf (dead before xf write)

  unsigned short* WgT  = WT + 0 * DH * DH;
  unsigned short* Wz0T = WT + 1 * DH * DH;
  unsigned short* Wz1T = WT + 2 * DH * DH;
  unsigned short* Wr0T = WT + 3 * DH * DH;
  unsigned short* Wr1T = WT + 4 * DH * DH;
  unsigned short* Wh0T = WT + 5 * DH * DH;
  unsigned short* Wh1T = WT + 6 * DH * DH;
  unsigned short* WembT= WT + 7 * DH * DH;

  hipLaunchKernelGGL(k_prep_w, dim3(9), dim3(256), 0, stream,
                     Wg, Wz0, Wz1, Wr0, Wr1, Wh0, Wh1, Wemb, We, WT, WeT);
  hipLaunchKernelGGL(k_emb_cvt, dim3(4096), dim3(256), 0, stream, embed, embB);
  hipLaunchKernelGGL(k_emb_mm, dim3(EMB_ROWS / 128), dim3(256), 0, stream, embB, WeT, T);
  hipLaunchKernelGGL(k_gather, dim3(2048), dim3(256), 0, stream, node_ids, T, be, xf, xb);
  for (int s = 0; s < 2; ++s) {
    hipLaunchKernelGGL(k_h, dim3(NNODES / 128), dim3(256), 0, stream,
                       xb, WgT, att_src, att_dst, h, a_s, a_d);
    hipLaunchKernelGGL(k_att, dim3(BGRAPH), dim3(512), 0, stream,
                       src, dst, h, a_s, a_d, bg, ab);
    hipLaunchKernelGGL(k_gru, dim3(NNODES / 64), dim3(256), 0, stream,
                       ab, xb, xf, Wz0T, Wz1T, Wr0T, Wr1T, Wh0T, Wh1T,
                       bz0, bz1, br0, br1, bh0, bh1);
  }
  hipLaunchKernelGGL(k_readout, dim3(BGRAPH), dim3(256), 0, stream, xb, WembT, Wmlp, out);
}

// Round 4
// 411.805 us; speedup vs baseline: 47.8150x; 1.1792x over previous
//
#include <hip/hip_runtime.h>
#include <hip/hip_bf16.h>

#define NNODES 131072
#define LGRAPH 256
#define BGRAPH 512
#define DIN 300
#define DH 96
#define EPG 2048
#define VOCAB 50001
#define NCLS 20
#define NEG 0.2f
#define EMB_ROWS 50048   // VOCAB padded to 128-row tiles
#define EMB_K 320        // 300 padded to 32-multiple
#define HTS 264          // padded LDS stride (halfs) for k_att transposed tiles
#define XS 104           // padded LDS stride (halfs) for k_gru tiles

typedef __attribute__((ext_vector_type(4))) float f32x4;
typedef __attribute__((ext_vector_type(8))) short bf16x8;
typedef __attribute__((ext_vector_type(8))) unsigned short u16x8;
#define MFMA16(a, b, c) __builtin_amdgcn_mfma_f32_16x16x32_bf16(a, b, c, 0, 0, 0)

__device__ __forceinline__ unsigned short f2b(float f) {
  __hip_bfloat16 h = __float2bfloat16(f);
  return *reinterpret_cast<unsigned short*>(&h);
}
__device__ __forceinline__ float b2f(unsigned short u) {
  __hip_bfloat16 h = *reinterpret_cast<__hip_bfloat16*>(&u);
  return __bfloat162float(h);
}
__device__ __forceinline__ float sigm(float v) { return 1.f / (1.f + __expf(-v)); }
__device__ __forceinline__ unsigned fenc(float f) {
  unsigned u = __float_as_uint(f);
  return (u & 0x80000000u) ? ~u : (u | 0x80000000u);
}
__device__ __forceinline__ float fdec(unsigned u) {
  return __uint_as_float((u & 0x80000000u) ? (u & 0x7fffffffu) : ~u);
}

// ---- weight prep: W[k][c] f32 -> WT[c][k] bf16 ; WeT ; combined biases ----
__global__ void k_prep_w(const float* __restrict__ Wg, const float* __restrict__ Wz0,
                         const float* __restrict__ Wz1, const float* __restrict__ Wr0,
                         const float* __restrict__ Wr1, const float* __restrict__ Wh0,
                         const float* __restrict__ Wh1, const float* __restrict__ Wemb,
                         const float* __restrict__ We,
                         const float* __restrict__ bz0, const float* __restrict__ bz1,
                         const float* __restrict__ br0, const float* __restrict__ br1,
                         const float* __restrict__ bh0, const float* __restrict__ bh1,
                         unsigned short* __restrict__ WT, unsigned short* __restrict__ WeT,
                         float* __restrict__ bc) {
  const int b = blockIdx.x, t = threadIdx.x;
  if (b < 8) {
    const float* src = (b == 0) ? Wg : (b == 1) ? Wz0 : (b == 2) ? Wz1 : (b == 3) ? Wr0
                     : (b == 4) ? Wr1 : (b == 5) ? Wh0 : (b == 6) ? Wh1 : Wemb;
    unsigned short* dst = WT + b * DH * DH;
    for (int i = t; i < DH * DH; i += 256) {
      int c = i / DH, k = i - c * DH;
      dst[i] = f2b(src[k * DH + c]);
    }
  } else if (b == 8) {
    for (int i = t; i < DH * EMB_K; i += 256) {
      int c = i / EMB_K, k = i - c * EMB_K;
      WeT[i] = (k < DIN) ? f2b(We[k * DH + c]) : (unsigned short)0;
    }
  } else {
    if (t < DH) {
      bc[t] = bz0[t] + bz1[t];
      bc[DH + t] = br0[t] + br1[t];
      bc[2 * DH + t] = bh0[t] + bh1[t];
    }
  }
}

// ---- embed f32 -> padded bf16 ----
__global__ void k_emb_cvt(const float* __restrict__ embed, unsigned short* __restrict__ embB) {
  const int total = EMB_ROWS * EMB_K;
  for (int i = blockIdx.x * blockDim.x + threadIdx.x; i < total;
       i += gridDim.x * blockDim.x) {
    int row = i / EMB_K, k = i - row * EMB_K;
    embB[i] = (row < VOCAB && k < DIN) ? f2b(embed[row * DIN + k]) : (unsigned short)0;
  }
}

// ---- Tb = embB @ We  (MFMA, M-tile 128, bf16 out) ----
__global__ void k_emb_mm(const unsigned short* __restrict__ embB,
                         const unsigned short* __restrict__ WeT,
                         unsigned short* __restrict__ Tb) {
  const int t = threadIdx.x, w = t >> 6, l = t & 63, li = l & 15, lh = l >> 4;
  const int wbase = blockIdx.x * 128 + w * 32;
  f32x4 acc[2][6];
  #pragma unroll
  for (int rt = 0; rt < 2; rt++)
    #pragma unroll
    for (int ct = 0; ct < 6; ct++) acc[rt][ct] = (f32x4)0.f;
  for (int ks = 0; ks < 10; ++ks) {
    const int ko = lh * 8 + ks * 32;
    bf16x8 aA0 = *(const bf16x8*)&embB[(wbase + li) * EMB_K + ko];
    bf16x8 aA1 = *(const bf16x8*)&embB[(wbase + 16 + li) * EMB_K + ko];
    #pragma unroll
    for (int ct = 0; ct < 6; ct++) {
      bf16x8 bB = *(const bf16x8*)&WeT[(ct * 16 + li) * EMB_K + ko];
      acc[0][ct] = MFMA16(aA0, bB, acc[0][ct]);
      acc[1][ct] = MFMA16(aA1, bB, acc[1][ct]);
    }
  }
  #pragma unroll
  for (int rt = 0; rt < 2; rt++)
    #pragma unroll
    for (int ct = 0; ct < 6; ct++)
      #pragma unroll
      for (int r = 0; r < 4; r++)
        Tb[(wbase + rt * 16 + lh * 4 + r) * DH + ct * 16 + li] = f2b(acc[rt][ct][r]);
}

// ---- x = tanh(Tb[ids] + be) -> bf16 ----
__global__ void k_gather(const int* __restrict__ ids, const unsigned short* __restrict__ Tb,
                         const float* __restrict__ be, unsigned short* __restrict__ xb) {
  const int total = NNODES * (DH / 8);
  for (int i = blockIdx.x * blockDim.x + threadIdx.x; i < total;
       i += gridDim.x * blockDim.x) {
    int n = i / (DH / 8);
    int q = i - n * (DH / 8);
    u16x8 v = *(const u16x8*)&Tb[ids[n] * DH + q * 8];
    u16x8 o;
    #pragma unroll
    for (int j = 0; j < 8; ++j) o[j] = f2b(tanhf(b2f(v[j]) + be[q * 8 + j]));
    *(u16x8*)&xb[i * 8] = o;
  }
}

// ---- h = xb @ Wg (bf16 out) + a_s/a_d row reductions (MFMA, M-tile 128) ----
__global__ void k_h(const unsigned short* __restrict__ xb,
                    const unsigned short* __restrict__ WgT,
                    const float* __restrict__ att_s, const float* __restrict__ att_d,
                    unsigned short* __restrict__ h, float* __restrict__ a_s,
                    float* __restrict__ a_d) {
  const int t = threadIdx.x, w = t >> 6, l = t & 63, li = l & 15, lh = l >> 4;
  const int wbase = blockIdx.x * 128 + w * 32;
  f32x4 acc[2][6];
  #pragma unroll
  for (int rt = 0; rt < 2; rt++)
    #pragma unroll
    for (int ct = 0; ct < 6; ct++) acc[rt][ct] = (f32x4)0.f;
  #pragma unroll
  for (int ks = 0; ks < 3; ++ks) {
    const int ko = lh * 8 + ks * 32;
    bf16x8 aA0 = *(const bf16x8*)&xb[(wbase + li) * DH + ko];
    bf16x8 aA1 = *(const bf16x8*)&xb[(wbase + 16 + li) * DH + ko];
    #pragma unroll
    for (int ct = 0; ct < 6; ct++) {
      bf16x8 bB = *(const bf16x8*)&WgT[(ct * 16 + li) * DH + ko];
      acc[0][ct] = MFMA16(aA0, bB, acc[0][ct]);
      acc[1][ct] = MFMA16(aA1, bB, acc[1][ct]);
    }
  }
  float ps[2][4] = {}, pd[2][4] = {};
  #pragma unroll
  for (int rt = 0; rt < 2; rt++)
    #pragma unroll
    for (int ct = 0; ct < 6; ct++) {
      const int col = ct * 16 + li;
      const float as_ = att_s[col], ad_ = att_d[col];
      #pragma unroll
      for (int r = 0; r < 4; r++) {
        float v = acc[rt][ct][r];
        h[(wbase + rt * 16 + lh * 4 + r) * DH + col] = f2b(v);
        ps[rt][r] += v * as_;
        pd[rt][r] += v * ad_;
      }
    }
  #pragma unroll
  for (int rt = 0; rt < 2; rt++)
    #pragma unroll
    for (int r = 0; r < 4; r++) {
      float s = ps[rt][r], d = pd[rt][r];
      #pragma unroll
      for (int m = 1; m < 16; m <<= 1) { s += __shfl_xor(s, m); d += __shfl_xor(d, m); }
      if (li == 0) {
        const int row = wbase + rt * 16 + lh * 4 + r;
        a_s[row] = s;
        a_d[row] = d;
      }
    }
}

// ---- per-graph GAT: softmax as dense P (unnormalized exp), a = inv_den*(P@h)+bg via MFMA ----
__global__ __launch_bounds__(512) void k_att(
    const int* __restrict__ src, const int* __restrict__ dst,
    const unsigned short* __restrict__ h, const float* __restrict__ a_sg,
    const float* __restrict__ a_dg, const float* __restrict__ bg,
    unsigned short* __restrict__ aout) {
  __shared__ __align__(16) unsigned short hT[DH * HTS];        // 50688 B, transposed h
  __shared__ __align__(16) float Pf[64 * LGRAPH];              // 65536 B (aliased by bf16 Pb)
  __shared__ float s_e[EPG];                                   // 8192 B: logits -> exp
  __shared__ unsigned char s_sl[EPG], s_dl[EPG];               // 4096 B
  __shared__ float s_as[LGRAPH], s_ad[LGRAPH];                 // 2048 B
  __shared__ float s_den[LGRAPH], s_inv[LGRAPH], s_selfex[LGRAPH];
  __shared__ unsigned s_m[LGRAPH];
  __shared__ float s_bg[DH];
  const int g = blockIdx.x, t = threadIdx.x;
  const int nb = g * LGRAPH;
  const int w = t >> 6, l = t & 63, li = l & 15, lh = l >> 4;

  // ---- phase 0: loads ----
  if (t < LGRAPH) {
    float as = a_sg[nb + t], ad = a_dg[nb + t];
    s_as[t] = as; s_ad[t] = ad;
    float se = as + ad; se = se > 0.f ? se : NEG * se;  // self-loop logit
    s_selfex[t] = se;
    s_m[t] = fenc(se);
  }
  if (t < DH) s_bg[t] = bg[t];
  for (int e = t; e < EPG; e += 512) {
    s_sl[e] = (unsigned char)(src[g * EPG + e] - nb);
    s_dl[e] = (unsigned char)(dst[g * EPG + e] - nb);
  }
  // stage h transposed: hT[col][row], padded stride
  for (int idx = t; idx < LGRAPH * (DH / 2); idx += 512) {
    int row = idx / (DH / 2), cp = idx - row * (DH / 2);
    unsigned v = ((const unsigned*)&h[(nb + row) * DH])[cp];
    hT[(2 * cp) * HTS + row] = (unsigned short)(v & 0xffff);
    hT[(2 * cp + 1) * HTS + row] = (unsigned short)(v >> 16);
  }
  __syncthreads();
  // ---- phase 1: edge logits + segment max ----
  for (int e = t; e < EPG; e += 512) {
    float ee = s_as[s_sl[e]] + s_ad[s_dl[e]];
    ee = ee > 0.f ? ee : NEG * ee;
    s_e[e] = ee;
    atomicMax(&s_m[s_dl[e]], fenc(ee));
  }
  __syncthreads();
  // ---- phase 2a: self exp, den init, stash m as float bits ----
  if (t < LGRAPH) {
    float m = fdec(s_m[t]);
    float sx = __expf(s_selfex[t] - m);
    s_selfex[t] = sx;
    s_den[t] = sx;
    s_m[t] = __float_as_uint(m);
  }
  __syncthreads();
  // ---- phase 2b: edge exp + den accumulate ----
  for (int e = t; e < EPG; e += 512) {
    int dl = s_dl[e];
    float ex = __expf(s_e[e] - __uint_as_float(s_m[dl]));
    s_e[e] = ex;
    atomicAdd(&s_den[dl], ex);
  }
  __syncthreads();
  if (t < LGRAPH) s_inv[t] = 1.f / s_den[t];
  __syncthreads();

  // ---- tiles of 64 dst rows: build P, pack bf16, MFMA ----
  unsigned short* Pb = (unsigned short*)Pf;   // packed [64][HTS]
  const int rb = w >> 1, ct0 = (w & 1) * 3;   // wave's output unit set
  for (int tb = 0; tb < 4; ++tb) {
    const int base = tb * 64;
    // zero
    for (int i = t; i < 64 * LGRAPH / 4; i += 512) ((float4*)Pf)[i] = make_float4(0.f, 0.f, 0.f, 0.f);
    __syncthreads();
    // scatter edges + self
    for (int e = t; e < EPG; e += 512) {
      unsigned r = (unsigned)(s_dl[e] - base);
      if (r < 64u) atomicAdd(&Pf[r * LGRAPH + s_sl[e]], s_e[e]);
    }
    if (t < 64) {
      int d = base + t;
      atomicAdd(&Pf[t * LGRAPH + d], s_selfex[d]);
    }
    __syncthreads();
    // pack f32 -> bf16 in place (read all to regs, sync, write padded)
    unsigned pk[16];
    #pragma unroll
    for (int i = 0; i < 16; ++i) {
      int wd = t + 512 * i;
      float2 v = *(const float2*)&Pf[2 * wd];
      pk[i] = (unsigned)f2b(v.x) | ((unsigned)f2b(v.y) << 16);
    }
    __syncthreads();
    #pragma unroll
    for (int i = 0; i < 16; ++i) {
      int wd = t + 512 * i;
      int r = wd >> 7, c2 = wd & 127;
      ((unsigned*)Pb)[r * (HTS / 2) + c2] = pk[i];
    }
    __syncthreads();
    // MFMA: 64 x 256 @ 256 x 96 ; wave does rows rb*16.. , cols ct0*16..(+3 tiles)
    f32x4 acc0 = (f32x4)0.f, acc1 = (f32x4)0.f, acc2 = (f32x4)0.f;
    #pragma unroll
    for (int ks = 0; ks < 8; ++ks) {
      const int ko = ks * 32 + lh * 8;
      bf16x8 aF = *(const bf16x8*)&Pb[(rb * 16 + li) * HTS + ko];
      bf16x8 b0 = *(const bf16x8*)&hT[(ct0 * 16 + li) * HTS + ko];
      bf16x8 b1 = *(const bf16x8*)&hT[((ct0 + 1) * 16 + li) * HTS + ko];
      bf16x8 b2 = *(const bf16x8*)&hT[((ct0 + 2) * 16 + li) * HTS + ko];
      acc0 = MFMA16(aF, b0, acc0);
      acc1 = MFMA16(aF, b1, acc1);
      acc2 = MFMA16(aF, b2, acc2);
    }
    // epilogue: a = acc * inv_den[row] + bg[col]
    #pragma unroll
    for (int r = 0; r < 4; ++r) {
      const int d = base + rb * 16 + lh * 4 + r;
      const float iv = s_inv[d];
      unsigned short* op = &aout[(nb + d) * DH];
      op[ct0 * 16 + li] = f2b(acc0[r] * iv + s_bg[ct0 * 16 + li]);
      op[(ct0 + 1) * 16 + li] = f2b(acc1[r] * iv + s_bg[(ct0 + 1) * 16 + li]);
      op[(ct0 + 2) * 16 + li] = f2b(acc2[r] * iv + s_bg[(ct0 + 2) * 16 + li]);
    }
    __syncthreads();   // Pb (=Pf) must be fully read before next tile zeroes it
  }
}

// ---- fused GRU, LDS-staged I/O: r -> u=x*r -> z,hh -> x update (MFMA, M-tile 64) ----
__global__ __launch_bounds__(256) void k_gru(
    const unsigned short* __restrict__ ab, unsigned short* __restrict__ xb,
    const unsigned short* __restrict__ Wz0T, const unsigned short* __restrict__ Wz1T,
    const unsigned short* __restrict__ Wr0T, const unsigned short* __restrict__ Wr1T,
    const unsigned short* __restrict__ Wh0T, const unsigned short* __restrict__ Wh1T,
    const float* __restrict__ bc) {
  __shared__ __align__(16) unsigned short sX[64 * XS];   // 13312 B each
  __shared__ __align__(16) unsigned short sA[64 * XS];
  __shared__ __align__(16) unsigned short sU[64 * XS];
  const int t = threadIdx.x, w = t >> 6, l = t & 63, li = l & 15, lh = l >> 4;
  const int nb0 = blockIdx.x * 64;
  // coalesced load of both tiles (64 rows x 96 cols bf16, 12 x 16B chunks/row)
  #pragma unroll
  for (int j = 0; j < 3; ++j) {
    int idx = t + 256 * j;                 // 768 chunks
    int row = idx / 12, ch = idx - row * 12;
    *(int4*)&sX[row * XS + ch * 8] = *(const int4*)&xb[nb0 * DH + row * DH + ch * 8];
    *(int4*)&sA[row * XS + ch * 8] = *(const int4*)&ab[nb0 * DH + row * DH + ch * 8];
  }
  __syncthreads();
  const int rbase = w * 16;
  // fragments
  bf16x8 aA[3], aX[3];
  #pragma unroll
  for (int ks = 0; ks < 3; ks++) {
    const int ko = lh * 8 + ks * 32;
    aA[ks] = *(const bf16x8*)&sA[(rbase + li) * XS + ko];
    aX[ks] = *(const bf16x8*)&sX[(rbase + li) * XS + ko];
  }
  // x in C-layout
  float xo[6][4];
  #pragma unroll
  for (int ct = 0; ct < 6; ct++)
    #pragma unroll
    for (int r = 0; r < 4; r++)
      xo[ct][r] = b2f(sX[(rbase + lh * 4 + r) * XS + ct * 16 + li]);
  // r gate
  f32x4 accR[6];
  #pragma unroll
  for (int ct = 0; ct < 6; ct++) accR[ct] = (f32x4)0.f;
  #pragma unroll
  for (int ks = 0; ks < 3; ks++) {
    const int ko = lh * 8 + ks * 32;
    #pragma unroll
    for (int ct = 0; ct < 6; ct++) {
      bf16x8 b0 = *(const bf16x8*)&Wr0T[(ct * 16 + li) * DH + ko];
      bf16x8 b1 = *(const bf16x8*)&Wr1T[(ct * 16 + li) * DH + ko];
      accR[ct] = MFMA16(aA[ks], b0, accR[ct]);
      accR[ct] = MFMA16(aX[ks], b1, accR[ct]);
    }
  }
  // u = x * sigmoid(r) -> sU (own rows only)
  #pragma unroll
  for (int ct = 0; ct < 6; ct++) {
    const int col = ct * 16 + li;
    const float rb = bc[DH + col];
    #pragma unroll
    for (int r = 0; r < 4; r++) {
      float rv = sigm(accR[ct][r] + rb);
      sU[(rbase + lh * 4 + r) * XS + col] = f2b(xo[ct][r] * rv);
    }
  }
  // z gate
  f32x4 accZ[6];
  #pragma unroll
  for (int ct = 0; ct < 6; ct++) accZ[ct] = (f32x4)0.f;
  #pragma unroll
  for (int ks = 0; ks < 3; ks++) {
    const int ko = lh * 8 + ks * 32;
    #pragma unroll
    for (int ct = 0; ct < 6; ct++) {
      bf16x8 b0 = *(const bf16x8*)&Wz0T[(ct * 16 + li) * DH + ko];
      bf16x8 b1 = *(const bf16x8*)&Wz1T[(ct * 16 + li) * DH + ko];
      accZ[ct] = MFMA16(aA[ks], b0, accZ[ct]);
      accZ[ct] = MFMA16(aX[ks], b1, accZ[ct]);
    }
  }
  // hh (aU from own rows; same-wave DS ops are in-order, no barrier needed)
  bf16x8 aU[3];
  #pragma unroll
  for (int ks = 0; ks < 3; ks++)
    aU[ks] = *(const bf16x8*)&sU[(rbase + li) * XS + lh * 8 + ks * 32];
  f32x4 accH[6];
  #pragma unroll
  for (int ct = 0; ct < 6; ct++) accH[ct] = (f32x4)0.f;
  #pragma unroll
  for (int ks = 0; ks < 3; ks++) {
    const int ko = lh * 8 + ks * 32;
    #pragma unroll
    for (int ct = 0; ct < 6; ct++) {
      bf16x8 b0 = *(const bf16x8*)&Wh0T[(ct * 16 + li) * DH + ko];
      bf16x8 b1 = *(const bf16x8*)&Wh1T[(ct * 16 + li) * DH + ko];
      accH[ct] = MFMA16(aA[ks], b0, accH[ct]);
      accH[ct] = MFMA16(aU[ks], b1, accH[ct]);
    }
  }
  // epilogue: xn -> sU (own rows, u values dead), then coalesced store
  #pragma unroll
  for (int ct = 0; ct < 6; ct++) {
    const int col = ct * 16 + li;
    const float zb = bc[col];
    const float hb = bc[2 * DH + col];
    #pragma unroll
    for (int r = 0; r < 4; r++) {
      float z = sigm(accZ[ct][r] + zb);
      float hh = tanhf(accH[ct][r] + hb);
      float xn = hh * z + xo[ct][r] * (1.f - z);
      sU[(rbase + lh * 4 + r) * XS + col] = f2b(xn);
    }
  }
  __syncthreads();
  #pragma unroll
  for (int j = 0; j < 3; ++j) {
    int idx = t + 256 * j;
    int row = idx / 12, ch = idx - row * 12;
    *(int4*)&xb[nb0 * DH + row * DH + ch * 8] = *(const int4*)&sU[row * XS + ch * 8];
  }
}

// ---- readout: y = tanh(xb @ Wemb); pool max+mean; out = pooled @ Wmlp ----
__global__ void k_readout(const unsigned short* __restrict__ xb,
                          const unsigned short* __restrict__ WembT,
                          const float* __restrict__ Wmlp, float* __restrict__ out) {
  __shared__ float pmaxs[4][DH], psums[4][DH];
  __shared__ float spool[DH];
  const int g = blockIdx.x, t = threadIdx.x, w = t >> 6, l = t & 63, li = l & 15, lh = l >> 4;
  const int wbase = g * LGRAPH + w * 64;
  f32x4 acc[4][6];
  #pragma unroll
  for (int rt = 0; rt < 4; rt++)
    #pragma unroll
    for (int ct = 0; ct < 6; ct++) acc[rt][ct] = (f32x4)0.f;
  #pragma unroll
  for (int ks = 0; ks < 3; ks++) {
    const int ko = lh * 8 + ks * 32;
    bf16x8 aA[4];
    #pragma unroll
    for (int rt = 0; rt < 4; rt++)
      aA[rt] = *(const bf16x8*)&xb[(wbase + rt * 16 + li) * DH + ko];
    #pragma unroll
    for (int ct = 0; ct < 6; ct++) {
      bf16x8 bB = *(const bf16x8*)&WembT[(ct * 16 + li) * DH + ko];
      #pragma unroll
      for (int rt = 0; rt < 4; rt++) acc[rt][ct] = MFMA16(aA[rt], bB, acc[rt][ct]);
    }
  }
  float pm[6], psu[6];
  #pragma unroll
  for (int ct = 0; ct < 6; ct++) {
    float mx = -1e30f, sm = 0.f;
    #pragma unroll
    for (int rt = 0; rt < 4; rt++)
      #pragma unroll
      for (int r = 0; r < 4; r++) {
        float y = tanhf(acc[rt][ct][r]);
        mx = fmaxf(mx, y);
        sm += y;
      }
    pm[ct] = mx; psu[ct] = sm;
  }
  #pragma unroll
  for (int ct = 0; ct < 6; ct++) {
    pm[ct] = fmaxf(pm[ct], __shfl_xor(pm[ct], 16));
    psu[ct] += __shfl_xor(psu[ct], 16);
    pm[ct] = fmaxf(pm[ct], __shfl_xor(pm[ct], 32));
    psu[ct] += __shfl_xor(psu[ct], 32);
  }
  if (lh == 0) {
    #pragma unroll
    for (int ct = 0; ct < 6; ct++) {
      pmaxs[w][ct * 16 + li] = pm[ct];
      psums[w][ct * 16 + li] = psu[ct];
    }
  }
  __syncthreads();
  if (t < DH) {
    float mx = fmaxf(fmaxf(pmaxs[0][t], pmaxs[1][t]), fmaxf(pmaxs[2][t], pmaxs[3][t]));
    float sm = psums[0][t] + psums[1][t] + psums[2][t] + psums[3][t];
    spool[t] = mx + sm * (1.f / LGRAPH);
  }
  __syncthreads();
  if (t < NCLS) {
    float a = 0.f;
    for (int k = 0; k < DH; ++k) a += spool[k] * Wmlp[k * NCLS + t];
    out[g * NCLS + t] = a;
  }
}

extern "C" void kernel_launch(void* const* d_in, const int* in_sizes, int n_in,
                              void* d_out, int out_size, void* d_ws, size_t ws_size,
                              hipStream_t stream) {
  const int*   node_ids = (const int*)d_in[0];
  const int*   src      = (const int*)d_in[1];
  const int*   dst      = (const int*)d_in[2];
  const float* embed    = (const float*)d_in[3];
  const float* We   = (const float*)d_in[4];
  const float* be   = (const float*)d_in[5];
  const float* Wg   = (const float*)d_in[6];
  const float* att_src = (const float*)d_in[7];
  const float* att_dst = (const float*)d_in[8];
  const float* bg   = (const float*)d_in[9];
  const float* Wz0  = (const float*)d_in[10];
  const float* bz0  = (const float*)d_in[11];
  const float* Wz1  = (const float*)d_in[12];
  const float* bz1  = (const float*)d_in[13];
  const float* Wr0  = (const float*)d_in[14];
  const float* br0  = (const float*)d_in[15];
  const float* Wr1  = (const float*)d_in[16];
  const float* br1  = (const float*)d_in[17];
  const float* Wh0  = (const float*)d_in[18];
  const float* bh0  = (const float*)d_in[19];
  const float* Wh1  = (const float*)d_in[20];
  const float* bh1  = (const float*)d_in[21];
  const float* Wemb = (const float*)d_in[22];
  const float* Wmlp = (const float*)d_in[23];
  float* out = (float*)d_out;

  char* w_ = (char*)d_ws;
  unsigned short* xb   = (unsigned short*)(w_ + 0);           // 25,165,824 B
  unsigned short* ab   = (unsigned short*)(w_ + 25165824);    // 25,165,824 B
  unsigned short* h    = (unsigned short*)(w_ + 50331648);    // 25,165,824 B
  unsigned short* Tb   = (unsigned short*)(w_ + 75497472);    // 9,609,216 B
  float*          a_s  = (float*)(w_ + 85106688);             // 524,288 B
  float*          a_d  = (float*)(w_ + 85630976);             // 524,288 B
  unsigned short* WT   = (unsigned short*)(w_ + 86155264);    // 147,456 B
  unsigned short* WeT  = (unsigned short*)(w_ + 86302720);    // 61,440 B
  float*          bc   = (float*)(w_ + 86364160);             // 1,152 B
  unsigned short* embB = (unsigned short*)(w_ + 0);           // 32 MB alias over xb+ab (dead before their writes)

  unsigned short* WgT  = WT + 0 * DH * DH;
  unsigned short* Wz0T = WT + 1 * DH * DH;
  unsigned short* Wz1T = WT + 2 * DH * DH;
  unsigned short* Wr0T = WT + 3 * DH * DH;
  unsigned short* Wr1T = WT + 4 * DH * DH;
  unsigned short* Wh0T = WT + 5 * DH * DH;
  unsigned short* Wh1T = WT + 6 * DH * DH;
  unsigned short* WembT= WT + 7 * DH * DH;

  hipLaunchKernelGGL(k_prep_w, dim3(10), dim3(256), 0, stream,
                     Wg, Wz0, Wz1, Wr0, Wr1, Wh0, Wh1, Wemb, We,
                     bz0, bz1, br0, br1, bh0, bh1, WT, WeT, bc);
  hipLaunchKernelGGL(k_emb_cvt, dim3(4096), dim3(256), 0, stream, embed, embB);
  hipLaunchKernelGGL(k_emb_mm, dim3(EMB_ROWS / 128), dim3(256), 0, stream, embB, WeT, Tb);
  hipLaunchKernelGGL(k_gather, dim3(2048), dim3(256), 0, stream, node_ids, Tb, be, xb);
  for (int s = 0; s < 2; ++s) {
    hipLaunchKernelGGL(k_h, dim3(NNODES / 128), dim3(256), 0, stream,
                       xb, WgT, att_src, att_dst, h, a_s, a_d);
    hipLaunchKernelGGL(k_att, dim3(BGRAPH), dim3(512), 0, stream,
                       src, dst, h, a_s, a_d, bg, ab);
    hipLaunchKernelGGL(k_gru, dim3(NNODES / 64), dim3(256), 0, stream,
                       ab, xb, Wz0T, Wz1T, Wr0T, Wr1T, Wh0T, Wh1T, bc);
  }
  hipLaunchKernelGGL(k_readout, dim3(BGRAPH), dim3(256), 0, stream, xb, WembT, Wmlp, out);
}

// Round 5
// 330.539 us; speedup vs baseline: 59.5708x; 1.2459x over previous
//
#include <hip/hip_runtime.h>
#include <hip/hip_bf16.h>

#define NNODES 131072
#define LGRAPH 256
#define BGRAPH 512
#define DIN 300
#define DH 96
#define EPG 2048
#define VOCAB 50001
#define NCLS 20
#define NEG 0.2f
#define EMB_ROWS 50048   // VOCAB padded to 128-row tiles
#define EMB_K 320        // 300 padded to 32-multiple
#define HTS 264          // padded LDS stride (halfs) for k_att transposed tiles
#define WS 100           // padded LDS stride (halfs) for k_gru weight/x tiles

typedef __attribute__((ext_vector_type(4))) float f32x4;
typedef __attribute__((ext_vector_type(8))) short bf16x8;
typedef __attribute__((ext_vector_type(8))) unsigned short u16x8;
#define MFMA16(a, b, c) __builtin_amdgcn_mfma_f32_16x16x32_bf16(a, b, c, 0, 0, 0)

__device__ __forceinline__ unsigned short f2b(float f) {
  __hip_bfloat16 h = __float2bfloat16(f);
  return *reinterpret_cast<unsigned short*>(&h);
}
__device__ __forceinline__ float b2f(unsigned short u) {
  __hip_bfloat16 h = *reinterpret_cast<__hip_bfloat16*>(&u);
  return __bfloat162float(h);
}
__device__ __forceinline__ float sigm(float v) { return 1.f / (1.f + __expf(-v)); }
__device__ __forceinline__ float ftanh(float x) {
  float ax = fabsf(x);
  float e = __expf(ax + ax);
  float t = 1.f - 2.f / (e + 1.f);
  return copysignf(t, x);
}
__device__ __forceinline__ unsigned fenc(float f) {
  unsigned u = __float_as_uint(f);
  return (u & 0x80000000u) ? ~u : (u | 0x80000000u);
}
__device__ __forceinline__ float fdec(unsigned u) {
  return __uint_as_float((u & 0x80000000u) ? (u & 0x7fffffffu) : ~u);
}

// ---- weight prep: W[k][c] f32 -> WT[c][k] bf16 ; WeT ; combined biases ----
__global__ void k_prep_w(const float* __restrict__ Wg, const float* __restrict__ Wz0,
                         const float* __restrict__ Wz1, const float* __restrict__ Wr0,
                         const float* __restrict__ Wr1, const float* __restrict__ Wh0,
                         const float* __restrict__ Wh1, const float* __restrict__ Wemb,
                         const float* __restrict__ We,
                         const float* __restrict__ bz0, const float* __restrict__ bz1,
                         const float* __restrict__ br0, const float* __restrict__ br1,
                         const float* __restrict__ bh0, const float* __restrict__ bh1,
                         unsigned short* __restrict__ WT, unsigned short* __restrict__ WeT,
                         float* __restrict__ bc) {
  const int b = blockIdx.x, t = threadIdx.x;
  if (b < 8) {
    const float* src = (b == 0) ? Wg : (b == 1) ? Wz0 : (b == 2) ? Wz1 : (b == 3) ? Wr0
                     : (b == 4) ? Wr1 : (b == 5) ? Wh0 : (b == 6) ? Wh1 : Wemb;
    unsigned short* dst = WT + b * DH * DH;
    for (int i = t; i < DH * DH; i += 256) {
      int c = i / DH, k = i - c * DH;
      dst[i] = f2b(src[k * DH + c]);
    }
  } else if (b == 8) {
    for (int i = t; i < DH * EMB_K; i += 256) {
      int c = i / EMB_K, k = i - c * EMB_K;
      WeT[i] = (k < DIN) ? f2b(We[k * DH + c]) : (unsigned short)0;
    }
  } else {
    if (t < DH) {
      bc[t] = bz0[t] + bz1[t];
      bc[DH + t] = br0[t] + br1[t];
      bc[2 * DH + t] = bh0[t] + bh1[t];
    }
  }
}

// ---- embed f32 -> padded bf16 ----
__global__ void k_emb_cvt(const float* __restrict__ embed, unsigned short* __restrict__ embB) {
  const int total = EMB_ROWS * EMB_K;
  for (int i = blockIdx.x * blockDim.x + threadIdx.x; i < total;
       i += gridDim.x * blockDim.x) {
    int row = i / EMB_K, k = i - row * EMB_K;
    embB[i] = (row < VOCAB && k < DIN) ? f2b(embed[row * DIN + k]) : (unsigned short)0;
  }
}

// ---- Tb = embB @ We  (MFMA, M-tile 128, bf16 out) ----
__global__ void k_emb_mm(const unsigned short* __restrict__ embB,
                         const unsigned short* __restrict__ WeT,
                         unsigned short* __restrict__ Tb) {
  const int t = threadIdx.x, w = t >> 6, l = t & 63, li = l & 15, lh = l >> 4;
  const int wbase = blockIdx.x * 128 + w * 32;
  f32x4 acc[2][6];
  #pragma unroll
  for (int rt = 0; rt < 2; rt++)
    #pragma unroll
    for (int ct = 0; ct < 6; ct++) acc[rt][ct] = (f32x4)0.f;
  for (int ks = 0; ks < 10; ++ks) {
    const int ko = lh * 8 + ks * 32;
    bf16x8 aA0 = *(const bf16x8*)&embB[(wbase + li) * EMB_K + ko];
    bf16x8 aA1 = *(const bf16x8*)&embB[(wbase + 16 + li) * EMB_K + ko];
    #pragma unroll
    for (int ct = 0; ct < 6; ct++) {
      bf16x8 bB = *(const bf16x8*)&WeT[(ct * 16 + li) * EMB_K + ko];
      acc[0][ct] = MFMA16(aA0, bB, acc[0][ct]);
      acc[1][ct] = MFMA16(aA1, bB, acc[1][ct]);
    }
  }
  #pragma unroll
  for (int rt = 0; rt < 2; rt++)
    #pragma unroll
    for (int ct = 0; ct < 6; ct++)
      #pragma unroll
      for (int r = 0; r < 4; r++)
        Tb[(wbase + rt * 16 + lh * 4 + r) * DH + ct * 16 + li] = f2b(acc[rt][ct][r]);
}

// ---- x = tanh(Tb[ids] + be) -> bf16 ----
__global__ void k_gather(const int* __restrict__ ids, const unsigned short* __restrict__ Tb,
                         const float* __restrict__ be, unsigned short* __restrict__ xb) {
  const int total = NNODES * (DH / 8);
  for (int i = blockIdx.x * blockDim.x + threadIdx.x; i < total;
       i += gridDim.x * blockDim.x) {
    int n = i / (DH / 8);
    int q = i - n * (DH / 8);
    u16x8 v = *(const u16x8*)&Tb[ids[n] * DH + q * 8];
    u16x8 o;
    #pragma unroll
    for (int j = 0; j < 8; ++j) o[j] = f2b(ftanh(b2f(v[j]) + be[q * 8 + j]));
    *(u16x8*)&xb[i * 8] = o;
  }
}

// ---- h = xb @ Wg (bf16 out) + a_s/a_d row reductions (MFMA, M-tile 128) ----
__global__ void k_h(const unsigned short* __restrict__ xb,
                    const unsigned short* __restrict__ WgT,
                    const float* __restrict__ att_s, const float* __restrict__ att_d,
                    unsigned short* __restrict__ h, float* __restrict__ a_s,
                    float* __restrict__ a_d) {
  const int t = threadIdx.x, w = t >> 6, l = t & 63, li = l & 15, lh = l >> 4;
  const int wbase = blockIdx.x * 128 + w * 32;
  f32x4 acc[2][6];
  #pragma unroll
  for (int rt = 0; rt < 2; rt++)
    #pragma unroll
    for (int ct = 0; ct < 6; ct++) acc[rt][ct] = (f32x4)0.f;
  #pragma unroll
  for (int ks = 0; ks < 3; ++ks) {
    const int ko = lh * 8 + ks * 32;
    bf16x8 aA0 = *(const bf16x8*)&xb[(wbase + li) * DH + ko];
    bf16x8 aA1 = *(const bf16x8*)&xb[(wbase + 16 + li) * DH + ko];
    #pragma unroll
    for (int ct = 0; ct < 6; ct++) {
      bf16x8 bB = *(const bf16x8*)&WgT[(ct * 16 + li) * DH + ko];
      acc[0][ct] = MFMA16(aA0, bB, acc[0][ct]);
      acc[1][ct] = MFMA16(aA1, bB, acc[1][ct]);
    }
  }
  float ps[2][4] = {}, pd[2][4] = {};
  #pragma unroll
  for (int rt = 0; rt < 2; rt++)
    #pragma unroll
    for (int ct = 0; ct < 6; ct++) {
      const int col = ct * 16 + li;
      const float as_ = att_s[col], ad_ = att_d[col];
      #pragma unroll
      for (int r = 0; r < 4; r++) {
        float v = acc[rt][ct][r];
        h[(wbase + rt * 16 + lh * 4 + r) * DH + col] = f2b(v);
        ps[rt][r] += v * as_;
        pd[rt][r] += v * ad_;
      }
    }
  #pragma unroll
  for (int rt = 0; rt < 2; rt++)
    #pragma unroll
    for (int r = 0; r < 4; r++) {
      float s = ps[rt][r], d = pd[rt][r];
      #pragma unroll
      for (int m = 1; m < 16; m <<= 1) { s += __shfl_xor(s, m); d += __shfl_xor(d, m); }
      if (li == 0) {
        const int row = wbase + rt * 16 + lh * 4 + r;
        a_s[row] = s;
        a_d[row] = d;
      }
    }
}

// ---- per-graph GAT: softmax as dense P (unnormalized exp), a = inv_den*(P@h)+bg via MFMA ----
__global__ __launch_bounds__(512) void k_att(
    const int* __restrict__ src, const int* __restrict__ dst,
    const unsigned short* __restrict__ h, const float* __restrict__ a_sg,
    const float* __restrict__ a_dg, const float* __restrict__ bg,
    unsigned short* __restrict__ aout) {
  __shared__ __align__(16) unsigned short hT[DH * HTS];        // 50688 B, transposed h
  __shared__ __align__(16) float Pf[64 * LGRAPH];              // 65536 B (aliased by bf16 Pb)
  __shared__ float s_e[EPG];                                   // 8192 B: logits -> exp
  __shared__ unsigned char s_sl[EPG], s_dl[EPG];               // 4096 B
  __shared__ float s_as[LGRAPH], s_ad[LGRAPH];                 // 2048 B
  __shared__ float s_den[LGRAPH], s_inv[LGRAPH], s_selfex[LGRAPH];
  __shared__ unsigned s_m[LGRAPH];
  __shared__ float s_bg[DH];
  const int g = blockIdx.x, t = threadIdx.x;
  const int nb = g * LGRAPH;
  const int w = t >> 6, l = t & 63, li = l & 15, lh = l >> 4;

  // ---- phase 0: loads ----
  if (t < LGRAPH) {
    float as = a_sg[nb + t], ad = a_dg[nb + t];
    s_as[t] = as; s_ad[t] = ad;
    float se = as + ad; se = se > 0.f ? se : NEG * se;  // self-loop logit
    s_selfex[t] = se;
    s_m[t] = fenc(se);
  }
  if (t < DH) s_bg[t] = bg[t];
  for (int e = t; e < EPG; e += 512) {
    s_sl[e] = (unsigned char)(src[g * EPG + e] - nb);
    s_dl[e] = (unsigned char)(dst[g * EPG + e] - nb);
  }
  // stage h transposed: hT[col][row], padded stride
  for (int idx = t; idx < LGRAPH * (DH / 2); idx += 512) {
    int row = idx / (DH / 2), cp = idx - row * (DH / 2);
    unsigned v = ((const unsigned*)&h[(nb + row) * DH])[cp];
    hT[(2 * cp) * HTS + row] = (unsigned short)(v & 0xffff);
    hT[(2 * cp + 1) * HTS + row] = (unsigned short)(v >> 16);
  }
  __syncthreads();
  // ---- phase 1: edge logits + segment max ----
  for (int e = t; e < EPG; e += 512) {
    float ee = s_as[s_sl[e]] + s_ad[s_dl[e]];
    ee = ee > 0.f ? ee : NEG * ee;
    s_e[e] = ee;
    atomicMax(&s_m[s_dl[e]], fenc(ee));
  }
  __syncthreads();
  // ---- phase 2a: self exp, den init, stash m as float bits ----
  if (t < LGRAPH) {
    float m = fdec(s_m[t]);
    float sx = __expf(s_selfex[t] - m);
    s_selfex[t] = sx;
    s_den[t] = sx;
    s_m[t] = __float_as_uint(m);
  }
  __syncthreads();
  // ---- phase 2b: edge exp + den accumulate ----
  for (int e = t; e < EPG; e += 512) {
    int dl = s_dl[e];
    float ex = __expf(s_e[e] - __uint_as_float(s_m[dl]));
    s_e[e] = ex;
    atomicAdd(&s_den[dl], ex);
  }
  __syncthreads();
  if (t < LGRAPH) s_inv[t] = 1.f / s_den[t];
  __syncthreads();

  // ---- tiles of 64 dst rows: build P, pack bf16, MFMA ----
  unsigned short* Pb = (unsigned short*)Pf;   // packed [64][HTS]
  const int rb = w >> 1, ct0 = (w & 1) * 3;   // wave's output unit set
  for (int tb = 0; tb < 4; ++tb) {
    const int base = tb * 64;
    // zero
    for (int i = t; i < 64 * LGRAPH / 4; i += 512) ((float4*)Pf)[i] = make_float4(0.f, 0.f, 0.f, 0.f);
    __syncthreads();
    // scatter edges + self
    for (int e = t; e < EPG; e += 512) {
      unsigned r = (unsigned)(s_dl[e] - base);
      if (r < 64u) atomicAdd(&Pf[r * LGRAPH + s_sl[e]], s_e[e]);
    }
    if (t < 64) {
      int d = base + t;
      atomicAdd(&Pf[t * LGRAPH + d], s_selfex[d]);
    }
    __syncthreads();
    // pack f32 -> bf16 in place (read all to regs, sync, write padded)
    unsigned pk[16];
    #pragma unroll
    for (int i = 0; i < 16; ++i) {
      int wd = t + 512 * i;
      float2 v = *(const float2*)&Pf[2 * wd];
      pk[i] = (unsigned)f2b(v.x) | ((unsigned)f2b(v.y) << 16);
    }
    __syncthreads();
    #pragma unroll
    for (int i = 0; i < 16; ++i) {
      int wd = t + 512 * i;
      int r = wd >> 7, c2 = wd & 127;
      ((unsigned*)Pb)[r * (HTS / 2) + c2] = pk[i];
    }
    __syncthreads();
    // MFMA: 64 x 256 @ 256 x 96 ; wave does rows rb*16.. , cols ct0*16..(+3 tiles)
    f32x4 acc0 = (f32x4)0.f, acc1 = (f32x4)0.f, acc2 = (f32x4)0.f;
    #pragma unroll
    for (int ks = 0; ks < 8; ++ks) {
      const int ko = ks * 32 + lh * 8;
      bf16x8 aF = *(const bf16x8*)&Pb[(rb * 16 + li) * HTS + ko];
      bf16x8 b0 = *(const bf16x8*)&hT[(ct0 * 16 + li) * HTS + ko];
      bf16x8 b1 = *(const bf16x8*)&hT[((ct0 + 1) * 16 + li) * HTS + ko];
      bf16x8 b2 = *(const bf16x8*)&hT[((ct0 + 2) * 16 + li) * HTS + ko];
      acc0 = MFMA16(aF, b0, acc0);
      acc1 = MFMA16(aF, b1, acc1);
      acc2 = MFMA16(aF, b2, acc2);
    }
    // epilogue: a = acc * inv_den[row] + bg[col]
    #pragma unroll
    for (int r = 0; r < 4; ++r) {
      const int d = base + rb * 16 + lh * 4 + r;
      const float iv = s_inv[d];
      unsigned short* op = &aout[(nb + d) * DH];
      op[ct0 * 16 + li] = f2b(acc0[r] * iv + s_bg[ct0 * 16 + li]);
      op[(ct0 + 1) * 16 + li] = f2b(acc1[r] * iv + s_bg[(ct0 + 1) * 16 + li]);
      op[(ct0 + 2) * 16 + li] = f2b(acc2[r] * iv + s_bg[(ct0 + 2) * 16 + li]);
    }
    __syncthreads();   // Pb (=Pf) must be fully read before next tile zeroes it
  }
}

// ---- fused GRU, persistent blocks, weights in LDS ----
// 256 blocks x 512 thr, 1 block/CU (LDS 140.8 KB). Each block: stage 6 weight
// mats (padded stride WS=100 -> conflict-free), loop 4 tiles of 128 nodes.
// Waves: (wr=w>>1) rows wr*32..+32, (wc=w&1) cols wc*48..+48.
__global__ __launch_bounds__(512, 2) void k_gru(
    const unsigned short* __restrict__ ab, unsigned short* __restrict__ xb,
    const unsigned short* __restrict__ WT, const float* __restrict__ bc) {
  __shared__ __align__(16) unsigned short sW[6 * DH * WS];   // 115200 B
  __shared__ __align__(16) unsigned short sX[128 * WS];      // 25600 B
  const int t = threadIdx.x, w = t >> 6, l = t & 63, li = l & 15, lh = l >> 4;
  const int wr = w >> 1, wc = w & 1;
  // stage weights: order Wr0,Wr1,Wz0,Wz1,Wh0,Wh1 (WT idx 3,4,1,2,5,6)
  #pragma unroll
  for (int m = 0; m < 6; ++m) {
    const int srcm = (m == 0) ? 3 : (m == 1) ? 4 : (m == 2) ? 1 : (m == 3) ? 2 : (m == 4) ? 5 : 6;
    const unsigned short* srcp = WT + srcm * DH * DH;
    for (int i = t; i < DH * 12; i += 512) {    // 1152 int4 chunks
      int r = i / 12, c8 = i - r * 12;
      *(int4*)&sW[(m * DH + r) * WS + c8 * 8] = *(const int4*)&srcp[r * DH + c8 * 8];
    }
  }
  // per-thread biases for owned cols
  float zb_[3], rb_[3], hb_[3];
  #pragma unroll
  for (int ct = 0; ct < 3; ++ct) {
    const int col = wc * 48 + ct * 16 + li;
    zb_[ct] = bc[col]; rb_[ct] = bc[DH + col]; hb_[ct] = bc[2 * DH + col];
  }

  for (int tile = 0; tile < 4; ++tile) {
    const int nb0 = (blockIdx.x * 4 + tile) * 128;
    __syncthreads();   // sX free (prev store done / weights staged)
    // stage x tile
    #pragma unroll
    for (int j = 0; j < 3; ++j) {
      int idx = t + 512 * j;                 // 1536 chunks
      int row = idx / 12, ch = idx - row * 12;
      *(int4*)&sX[row * WS + ch * 8] = *(const int4*)&xb[(nb0 + row) * DH + ch * 8];
    }
    __syncthreads();
    // fragments: a from global (L2-resident, single-use), x from LDS
    bf16x8 aA[2][3], aX[2][3];
    #pragma unroll
    for (int rt = 0; rt < 2; rt++)
      #pragma unroll
      for (int ks = 0; ks < 3; ks++) {
        const int row = wr * 32 + rt * 16 + li;
        const int ko = lh * 8 + ks * 32;
        aA[rt][ks] = *(const bf16x8*)&ab[(nb0 + row) * DH + ko];
        aX[rt][ks] = *(const bf16x8*)&sX[row * WS + ko];
      }
    float xo[2][3][4];
    #pragma unroll
    for (int rt = 0; rt < 2; rt++)
      #pragma unroll
      for (int ct = 0; ct < 3; ct++)
        #pragma unroll
        for (int r = 0; r < 4; r++)
          xo[rt][ct][r] = b2f(sX[(wr * 32 + rt * 16 + lh * 4 + r) * WS + wc * 48 + ct * 16 + li]);
    // r and z gates together (both consume aA/aX only)
    f32x4 accR[2][3], accZ[2][3];
    #pragma unroll
    for (int rt = 0; rt < 2; rt++)
      #pragma unroll
      for (int ct = 0; ct < 3; ct++) { accR[rt][ct] = (f32x4)0.f; accZ[rt][ct] = (f32x4)0.f; }
    #pragma unroll
    for (int ks = 0; ks < 3; ks++) {
      const int ko = lh * 8 + ks * 32;
      #pragma unroll
      for (int ct = 0; ct < 3; ct++) {
        const int wrow = wc * 48 + ct * 16 + li;
        bf16x8 w_r0 = *(const bf16x8*)&sW[(0 * DH + wrow) * WS + ko];
        bf16x8 w_r1 = *(const bf16x8*)&sW[(1 * DH + wrow) * WS + ko];
        bf16x8 w_z0 = *(const bf16x8*)&sW[(2 * DH + wrow) * WS + ko];
        bf16x8 w_z1 = *(const bf16x8*)&sW[(3 * DH + wrow) * WS + ko];
        #pragma unroll
        for (int rt = 0; rt < 2; rt++) {
          accR[rt][ct] = MFMA16(aA[rt][ks], w_r0, accR[rt][ct]);
          accR[rt][ct] = MFMA16(aX[rt][ks], w_r1, accR[rt][ct]);
          accZ[rt][ct] = MFMA16(aA[rt][ks], w_z0, accZ[rt][ct]);
          accZ[rt][ct] = MFMA16(aX[rt][ks], w_z1, accZ[rt][ct]);
        }
      }
    }
    __syncthreads();   // all sX reads (aX, xo) complete
    // u = x * sigmoid(r) into sX (in place)
    #pragma unroll
    for (int rt = 0; rt < 2; rt++)
      #pragma unroll
      for (int ct = 0; ct < 3; ct++) {
        const int col = wc * 48 + ct * 16 + li;
        #pragma unroll
        for (int r = 0; r < 4; r++) {
          float rv = sigm(accR[rt][ct][r] + rb_[ct]);
          sX[(wr * 32 + rt * 16 + lh * 4 + r) * WS + col] = f2b(xo[rt][ct][r] * rv);
        }
      }
    __syncthreads();   // u visible
    bf16x8 aU[2][3];
    #pragma unroll
    for (int rt = 0; rt < 2; rt++)
      #pragma unroll
      for (int ks = 0; ks < 3; ks++)
        aU[rt][ks] = *(const bf16x8*)&sX[(wr * 32 + rt * 16 + li) * WS + lh * 8 + ks * 32];
    __syncthreads();   // all aU reads complete before xn overwrite
    f32x4 accH[2][3];
    #pragma unroll
    for (int rt = 0; rt < 2; rt++)
      #pragma unroll
      for (int ct = 0; ct < 3; ct++) accH[rt][ct] = (f32x4)0.f;
    #pragma unroll
    for (int ks = 0; ks < 3; ks++) {
      const int ko = lh * 8 + ks * 32;
      #pragma unroll
      for (int ct = 0; ct < 3; ct++) {
        const int wrow = wc * 48 + ct * 16 + li;
        bf16x8 w_h0 = *(const bf16x8*)&sW[(4 * DH + wrow) * WS + ko];
        bf16x8 w_h1 = *(const bf16x8*)&sW[(5 * DH + wrow) * WS + ko];
        #pragma unroll
        for (int rt = 0; rt < 2; rt++) {
          accH[rt][ct] = MFMA16(aA[rt][ks], w_h0, accH[rt][ct]);
          accH[rt][ct] = MFMA16(aU[rt][ks], w_h1, accH[rt][ct]);
        }
      }
    }
    // epilogue: xn into sX, then coalesced store
    #pragma unroll
    for (int rt = 0; rt < 2; rt++)
      #pragma unroll
      for (int ct = 0; ct < 3; ct++) {
        const int col = wc * 48 + ct * 16 + li;
        #pragma unroll
        for (int r = 0; r < 4; r++) {
          float z = sigm(accZ[rt][ct][r] + zb_[ct]);
          float hh = ftanh(accH[rt][ct][r] + hb_[ct]);
          float xn = hh * z + xo[rt][ct][r] * (1.f - z);
          sX[(wr * 32 + rt * 16 + lh * 4 + r) * WS + col] = f2b(xn);
        }
      }
    __syncthreads();
    #pragma unroll
    for (int j = 0; j < 3; ++j) {
      int idx = t + 512 * j;
      int row = idx / 12, ch = idx - row * 12;
      *(int4*)&xb[(nb0 + row) * DH + ch * 8] = *(const int4*)&sX[row * WS + ch * 8];
    }
  }
}

// ---- readout: y = tanh(xb @ Wemb); pool max+mean; out = pooled @ Wmlp ----
__global__ void k_readout(const unsigned short* __restrict__ xb,
                          const unsigned short* __restrict__ WembT,
                          const float* __restrict__ Wmlp, float* __restrict__ out) {
  __shared__ float pmaxs[4][DH], psums[4][DH];
  __shared__ float spool[DH];
  const int g = blockIdx.x, t = threadIdx.x, w = t >> 6, l = t & 63, li = l & 15, lh = l >> 4;
  const int wbase = g * LGRAPH + w * 64;
  f32x4 acc[4][6];
  #pragma unroll
  for (int rt = 0; rt < 4; rt++)
    #pragma unroll
    for (int ct = 0; ct < 6; ct++) acc[rt][ct] = (f32x4)0.f;
  #pragma unroll
  for (int ks = 0; ks < 3; ks++) {
    const int ko = lh * 8 + ks * 32;
    bf16x8 aA[4];
    #pragma unroll
    for (int rt = 0; rt < 4; rt++)
      aA[rt] = *(const bf16x8*)&xb[(wbase + rt * 16 + li) * DH + ko];
    #pragma unroll
    for (int ct = 0; ct < 6; ct++) {
      bf16x8 bB = *(const bf16x8*)&WembT[(ct * 16 + li) * DH + ko];
      #pragma unroll
      for (int rt = 0; rt < 4; rt++) acc[rt][ct] = MFMA16(aA[rt], bB, acc[rt][ct]);
    }
  }
  float pm[6], psu[6];
  #pragma unroll
  for (int ct = 0; ct < 6; ct++) {
    float mx = -1e30f, sm = 0.f;
    #pragma unroll
    for (int rt = 0; rt < 4; rt++)
      #pragma unroll
      for (int r = 0; r < 4; r++) {
        float y = ftanh(acc[rt][ct][r]);
        mx = fmaxf(mx, y);
        sm += y;
      }
    pm[ct] = mx; psu[ct] = sm;
  }
  #pragma unroll
  for (int ct = 0; ct < 6; ct++) {
    pm[ct] = fmaxf(pm[ct], __shfl_xor(pm[ct], 16));
    psu[ct] += __shfl_xor(psu[ct], 16);
    pm[ct] = fmaxf(pm[ct], __shfl_xor(pm[ct], 32));
    psu[ct] += __shfl_xor(psu[ct], 32);
  }
  if (lh == 0) {
    #pragma unroll
    for (int ct = 0; ct < 6; ct++) {
      pmaxs[w][ct * 16 + li] = pm[ct];
      psums[w][ct * 16 + li] = psu[ct];
    }
  }
  __syncthreads();
  if (t < DH) {
    float mx = fmaxf(fmaxf(pmaxs[0][t], pmaxs[1][t]), fmaxf(pmaxs[2][t], pmaxs[3][t]));
    float sm = psums[0][t] + psums[1][t] + psums[2][t] + psums[3][t];
    spool[t] = mx + sm * (1.f / LGRAPH);
  }
  __syncthreads();
  if (t < NCLS) {
    float a = 0.f;
    for (int k = 0; k < DH; ++k) a += spool[k] * Wmlp[k * NCLS + t];
    out[g * NCLS + t] = a;
  }
}

extern "C" void kernel_launch(void* const* d_in, const int* in_sizes, int n_in,
                              void* d_out, int out_size, void* d_ws, size_t ws_size,
                              hipStream_t stream) {
  const int*   node_ids = (const int*)d_in[0];
  const int*   src      = (const int*)d_in[1];
  const int*   dst      = (const int*)d_in[2];
  const float* embed    = (const float*)d_in[3];
  const float* We   = (const float*)d_in[4];
  const float* be   = (const float*)d_in[5];
  const float* Wg   = (const float*)d_in[6];
  const float* att_src = (const float*)d_in[7];
  const float* att_dst = (const float*)d_in[8];
  const float* bg   = (const float*)d_in[9];
  const float* Wz0  = (const float*)d_in[10];
  const float* bz0  = (const float*)d_in[11];
  const float* Wz1  = (const float*)d_in[12];
  const float* bz1  = (const float*)d_in[13];
  const float* Wr0  = (const float*)d_in[14];
  const float* br0  = (const float*)d_in[15];
  const float* Wr1  = (const float*)d_in[16];
  const float* br1  = (const float*)d_in[17];
  const float* Wh0  = (const float*)d_in[18];
  const float* bh0  = (const float*)d_in[19];
  const float* Wh1  = (const float*)d_in[20];
  const float* bh1  = (const float*)d_in[21];
  const float* Wemb = (const float*)d_in[22];
  const float* Wmlp = (const float*)d_in[23];
  float* out = (float*)d_out;

  char* w_ = (char*)d_ws;
  unsigned short* xb   = (unsigned short*)(w_ + 0);           // 25,165,824 B
  unsigned short* ab   = (unsigned short*)(w_ + 25165824);    // 25,165,824 B
  unsigned short* h    = (unsigned short*)(w_ + 50331648);    // 25,165,824 B
  unsigned short* Tb   = (unsigned short*)(w_ + 75497472);    // 9,609,216 B
  float*          a_s  = (float*)(w_ + 85106688);             // 524,288 B
  float*          a_d  = (float*)(w_ + 85630976);             // 524,288 B
  unsigned short* WT   = (unsigned short*)(w_ + 86155264);    // 147,456 B
  unsigned short* WeT  = (unsigned short*)(w_ + 86302720);    // 61,440 B
  float*          bc   = (float*)(w_ + 86364160);             // 1,152 B
  unsigned short* embB = (unsigned short*)(w_ + 0);           // 32 MB alias over xb+ab (dead before their writes)

  unsigned short* WgT  = WT + 0 * DH * DH;
  unsigned short* WembT= WT + 7 * DH * DH;

  hipLaunchKernelGGL(k_prep_w, dim3(10), dim3(256), 0, stream,
                     Wg, Wz0, Wz1, Wr0, Wr1, Wh0, Wh1, Wemb, We,
                     bz0, bz1, br0, br1, bh0, bh1, WT, WeT, bc);
  hipLaunchKernelGGL(k_emb_cvt, dim3(4096), dim3(256), 0, stream, embed, embB);
  hipLaunchKernelGGL(k_emb_mm, dim3(EMB_ROWS / 128), dim3(256), 0, stream, embB, WeT, Tb);
  hipLaunchKernelGGL(k_gather, dim3(2048), dim3(256), 0, stream, node_ids, Tb, be, xb);
  for (int s = 0; s < 2; ++s) {
    hipLaunchKernelGGL(k_h, dim3(NNODES / 128), dim3(256), 0, stream,
                       xb, WgT, att_src, att_dst, h, a_s, a_d);
    hipLaunchKernelGGL(k_att, dim3(BGRAPH), dim3(512), 0, stream,
                       src, dst, h, a_s, a_d, bg, ab);
    hipLaunchKernelGGL(k_gru, dim3(256), dim3(512), 0, stream, ab, xb, WT, bc);
  }
  hipLaunchKernelGGL(k_readout, dim3(BGRAPH), dim3(256), 0, stream, xb, WembT, Wmlp, out);
}

// Round 6
// 246.032 us; speedup vs baseline: 80.0323x; 1.3435x over previous
//
#include <hip/hip_runtime.h>
#include <hip/hip_bf16.h>

#define NNODES 131072
#define LGRAPH 256
#define BGRAPH 512
#define DIN 300
#define DH 96
#define EPG 2048
#define VOCAB 50001
#define NCLS 20
#define NEG 0.2f
#define EMB_ROWS 50048   // VOCAB padded to 128-row tiles
#define EMB_K 320        // 300 padded to 32-multiple
#define WS 100           // padded LDS stride (halfs) for weight tiles
#define XS 104           // padded LDS stride (halfs) for x/h tiles

typedef __attribute__((ext_vector_type(4))) float f32x4;
typedef __attribute__((ext_vector_type(8))) short bf16x8;
typedef __attribute__((ext_vector_type(8))) unsigned short u16x8;
#define MFMA16(a, b, c) __builtin_amdgcn_mfma_f32_16x16x32_bf16(a, b, c, 0, 0, 0)

__device__ __forceinline__ unsigned short f2b(float f) {
  __hip_bfloat16 h = __float2bfloat16(f);
  return *reinterpret_cast<unsigned short*>(&h);
}
__device__ __forceinline__ float b2f(unsigned short u) {
  unsigned v = ((unsigned)u) << 16;
  return __uint_as_float(v);
}
__device__ __forceinline__ float sigm(float v) { return 1.f / (1.f + __expf(-v)); }
__device__ __forceinline__ float ftanh(float x) {
  float ax = fabsf(x);
  float e = __expf(ax + ax);
  float t = 1.f - 2.f / (e + 1.f);
  return copysignf(t, x);
}

// ---- weight prep: W[k][c] f32 -> WT[c][k] bf16 ; WeT ; combined biases ----
__global__ void k_prep_w(const float* __restrict__ Wg, const float* __restrict__ Wz0,
                         const float* __restrict__ Wz1, const float* __restrict__ Wr0,
                         const float* __restrict__ Wr1, const float* __restrict__ Wh0,
                         const float* __restrict__ Wh1, const float* __restrict__ Wemb,
                         const float* __restrict__ We,
                         const float* __restrict__ bz0, const float* __restrict__ bz1,
                         const float* __restrict__ br0, const float* __restrict__ br1,
                         const float* __restrict__ bh0, const float* __restrict__ bh1,
                         unsigned short* __restrict__ WT, unsigned short* __restrict__ WeT,
                         float* __restrict__ bc) {
  const int b = blockIdx.x, t = threadIdx.x;
  if (b < 8) {
    const float* src = (b == 0) ? Wg : (b == 1) ? Wz0 : (b == 2) ? Wz1 : (b == 3) ? Wr0
                     : (b == 4) ? Wr1 : (b == 5) ? Wh0 : (b == 6) ? Wh1 : Wemb;
    unsigned short* dst = WT + b * DH * DH;
    for (int i = t; i < DH * DH; i += 256) {
      int c = i / DH, k = i - c * DH;
      dst[i] = f2b(src[k * DH + c]);
    }
  } else if (b == 8) {
    for (int i = t; i < DH * EMB_K; i += 256) {
      int c = i / EMB_K, k = i - c * EMB_K;
      WeT[i] = (k < DIN) ? f2b(We[k * DH + c]) : (unsigned short)0;
    }
  } else {
    if (t < DH) {
      bc[t] = bz0[t] + bz1[t];
      bc[DH + t] = br0[t] + br1[t];
      bc[2 * DH + t] = bh0[t] + bh1[t];
    }
  }
}

// ---- Tb = embed @ We  (MFMA, M-tile 128, f32 A converted in-reg, bf16 out) ----
__device__ __forceinline__ bf16x8 ldcvt(const float* __restrict__ p, int row, int ko) {
  bf16x8 r;
  if (row < VOCAB) {
    float4 c0 = (ko + 4 <= DIN) ? *(const float4*)&p[row * DIN + ko]
                                : make_float4(0.f, 0.f, 0.f, 0.f);
    float4 c1 = (ko + 8 <= DIN) ? *(const float4*)&p[row * DIN + ko + 4]
                                : make_float4(0.f, 0.f, 0.f, 0.f);
    r[0] = (short)f2b(c0.x); r[1] = (short)f2b(c0.y);
    r[2] = (short)f2b(c0.z); r[3] = (short)f2b(c0.w);
    r[4] = (short)f2b(c1.x); r[5] = (short)f2b(c1.y);
    r[6] = (short)f2b(c1.z); r[7] = (short)f2b(c1.w);
  } else {
    #pragma unroll
    for (int j = 0; j < 8; ++j) r[j] = 0;
  }
  return r;
}

__global__ void k_emb_mm(const float* __restrict__ embed,
                         const unsigned short* __restrict__ WeT,
                         unsigned short* __restrict__ Tb) {
  const int t = threadIdx.x, w = t >> 6, l = t & 63, li = l & 15, lh = l >> 4;
  const int wbase = blockIdx.x * 128 + w * 32;
  f32x4 acc[2][6];
  #pragma unroll
  for (int rt = 0; rt < 2; rt++)
    #pragma unroll
    for (int ct = 0; ct < 6; ct++) acc[rt][ct] = (f32x4)0.f;
  for (int ks = 0; ks < 10; ++ks) {
    const int ko = lh * 8 + ks * 32;
    bf16x8 aA0 = ldcvt(embed, wbase + li, ko);
    bf16x8 aA1 = ldcvt(embed, wbase + 16 + li, ko);
    #pragma unroll
    for (int ct = 0; ct < 6; ct++) {
      bf16x8 bB = *(const bf16x8*)&WeT[(ct * 16 + li) * EMB_K + ko];
      acc[0][ct] = MFMA16(aA0, bB, acc[0][ct]);
      acc[1][ct] = MFMA16(aA1, bB, acc[1][ct]);
    }
  }
  #pragma unroll
  for (int rt = 0; rt < 2; rt++)
    #pragma unroll
    for (int ct = 0; ct < 6; ct++)
      #pragma unroll
      for (int r = 0; r < 4; r++)
        Tb[(wbase + rt * 16 + lh * 4 + r) * DH + ct * 16 + li] = f2b(acc[rt][ct][r]);
}

// ---- x = tanh(Tb[ids] + be) -> bf16 ----
__global__ void k_gather(const int* __restrict__ ids, const unsigned short* __restrict__ Tb,
                         const float* __restrict__ be, unsigned short* __restrict__ xb) {
  const int total = NNODES * (DH / 8);
  for (int i = blockIdx.x * blockDim.x + threadIdx.x; i < total;
       i += gridDim.x * blockDim.x) {
    int n = i / (DH / 8);
    int q = i - n * (DH / 8);
    u16x8 v = *(const u16x8*)&Tb[ids[n] * DH + q * 8];
    u16x8 o;
    #pragma unroll
    for (int j = 0; j < 8; ++j) o[j] = f2b(ftanh(b2f(v[j]) + be[q * 8 + j]));
    *(u16x8*)&xb[i * 8] = o;
  }
}

// ---- h = xb @ Wg (bf16 out) + a_s/a_d row reductions (MFMA, M-tile 128, W in LDS) ----
__global__ __launch_bounds__(256) void k_h(
    const unsigned short* __restrict__ xb, const unsigned short* __restrict__ WgT,
    const float* __restrict__ att_s, const float* __restrict__ att_d,
    unsigned short* __restrict__ h, float* __restrict__ a_s,
    float* __restrict__ a_d) {
  __shared__ __align__(16) unsigned short sW[DH * WS];   // 19200 B
  const int t = threadIdx.x, w = t >> 6, l = t & 63, li = l & 15, lh = l >> 4;
  const int wbase = blockIdx.x * 128 + w * 32;
  for (int i = t; i < DH * 12; i += 256) {
    int r = i / 12, c8 = i - r * 12;
    *(int4*)&sW[r * WS + c8 * 8] = *(const int4*)&WgT[r * DH + c8 * 8];
  }
  __syncthreads();
  f32x4 acc[2][6];
  #pragma unroll
  for (int rt = 0; rt < 2; rt++)
    #pragma unroll
    for (int ct = 0; ct < 6; ct++) acc[rt][ct] = (f32x4)0.f;
  #pragma unroll
  for (int ks = 0; ks < 3; ++ks) {
    const int ko = lh * 8 + ks * 32;
    bf16x8 aA0 = *(const bf16x8*)&xb[(wbase + li) * DH + ko];
    bf16x8 aA1 = *(const bf16x8*)&xb[(wbase + 16 + li) * DH + ko];
    #pragma unroll
    for (int ct = 0; ct < 6; ct++) {
      bf16x8 bB = *(const bf16x8*)&sW[(ct * 16 + li) * WS + ko];
      acc[0][ct] = MFMA16(aA0, bB, acc[0][ct]);
      acc[1][ct] = MFMA16(aA1, bB, acc[1][ct]);
    }
  }
  float ps[2][4] = {}, pd[2][4] = {};
  #pragma unroll
  for (int rt = 0; rt < 2; rt++)
    #pragma unroll
    for (int ct = 0; ct < 6; ct++) {
      const int col = ct * 16 + li;
      const float as_ = att_s[col], ad_ = att_d[col];
      #pragma unroll
      for (int r = 0; r < 4; r++) {
        float v = acc[rt][ct][r];
        h[(wbase + rt * 16 + lh * 4 + r) * DH + col] = f2b(v);
        ps[rt][r] += v * as_;
        pd[rt][r] += v * ad_;
      }
    }
  #pragma unroll
  for (int rt = 0; rt < 2; rt++)
    #pragma unroll
    for (int r = 0; r < 4; r++) {
      float s = ps[rt][r], d = pd[rt][r];
      #pragma unroll
      for (int m = 1; m < 16; m <<= 1) { s += __shfl_xor(s, m); d += __shfl_xor(d, m); }
      if (li == 0) {
        const int row = wbase + rt * 16 + lh * 4 + r;
        a_s[row] = s;
        a_d[row] = d;
      }
    }
}

// ---- per-graph GAT via CSR gather: a[d] = (sum_e exp(e-m)*h[src] + self)/den + bg ----
// 512 thr: 2 threads per dst node (48 cols each). LDS 73 KB -> 2 blocks/CU.
__global__ __launch_bounds__(512, 4) void k_att(
    const int* __restrict__ src, const int* __restrict__ dst,
    const unsigned short* __restrict__ h, const float* __restrict__ a_sg,
    const float* __restrict__ a_dg, const float* __restrict__ bg,
    unsigned short* __restrict__ aout) {
  __shared__ __align__(16) unsigned short sH[LGRAPH * XS];  // 53248 B
  __shared__ float s_ev[EPG];                               // 8192 B (CSR logits)
  __shared__ unsigned char s_sl[EPG], s_dl[EPG];            // 4096 B
  __shared__ unsigned char s_srcS[EPG];                     // 2048 B (CSR src)
  __shared__ int s_cnt[LGRAPH], s_off[LGRAPH], s_pos[LGRAPH]; // 3072 B
  __shared__ float s_as[LGRAPH], s_ad[LGRAPH];              // 2048 B
  __shared__ float s_bg[DH];                                // 384 B
  const int g = blockIdx.x, t = threadIdx.x;
  const int nb = g * LGRAPH;
  // phase 0: init + stage
  if (t < LGRAPH) { s_cnt[t] = 0; s_as[t] = a_sg[nb + t]; s_ad[t] = a_dg[nb + t]; }
  if (t < DH) s_bg[t] = bg[t];
  #pragma unroll
  for (int j = 0; j < 6; ++j) {
    int idx = t + 512 * j;                 // 3072 chunks = 256 rows x 12
    int row = idx / 12, ch = idx - row * 12;
    *(int4*)&sH[row * XS + ch * 8] = *(const int4*)&h[(nb + row) * DH + ch * 8];
  }
  __syncthreads();
  // phase 1: load edges + count in-degree
  for (int e = t; e < EPG; e += 512) {
    int sl = src[g * EPG + e] - nb, dl = dst[g * EPG + e] - nb;
    s_sl[e] = (unsigned char)sl;
    s_dl[e] = (unsigned char)dl;
    atomicAdd(&s_cnt[dl], 1);
  }
  __syncthreads();
  // phase 2: exclusive prefix scan (wave 0, shuffle)
  if (t < 64) {
    int carry = 0;
    #pragma unroll
    for (int c = 0; c < 4; ++c) {
      int v = s_cnt[c * 64 + t];
      int x = v;
      #pragma unroll
      for (int o = 1; o < 64; o <<= 1) {
        int y = __shfl_up(x, o);
        if (t >= o) x += y;
      }
      s_off[c * 64 + t] = x - v + carry;
      carry += __shfl(x, 63);
    }
  }
  __syncthreads();
  if (t < LGRAPH) s_pos[t] = s_off[t];
  __syncthreads();
  // phase 3: scatter edges into CSR order with logits
  for (int e = t; e < EPG; e += 512) {
    int sl = s_sl[e], dl = s_dl[e];
    float ee = s_as[sl] + s_ad[dl];
    ee = ee > 0.f ? ee : NEG * ee;
    int pos = atomicAdd(&s_pos[dl], 1);
    s_srcS[pos] = (unsigned char)sl;
    s_ev[pos] = ee;
  }
  __syncthreads();
  // phase 4: gather. d = t>>1, cols (t&1)*48..+48
  {
    const int d = t >> 1, half = t & 1;
    const int beg = s_off[d], end = beg + s_cnt[d];
    float ss = s_as[d] + s_ad[d];
    ss = ss > 0.f ? ss : NEG * ss;
    float m = ss;
    for (int i = beg; i < end; ++i) m = fmaxf(m, s_ev[i]);
    const int cbase = half * 48;
    float acc[48];
    float wself = __expf(ss - m);
    float den = wself;
    #pragma unroll
    for (int k = 0; k < 6; ++k) {
      u16x8 v = *(const u16x8*)&sH[d * XS + cbase + k * 8];
      #pragma unroll
      for (int j = 0; j < 8; ++j) acc[k * 8 + j] = wself * b2f(v[j]);
    }
    for (int i = beg; i < end; ++i) {
      float wv = __expf(s_ev[i] - m);
      den += wv;
      int sl2 = s_srcS[i];
      #pragma unroll
      for (int k = 0; k < 6; ++k) {
        u16x8 v = *(const u16x8*)&sH[sl2 * XS + cbase + k * 8];
        #pragma unroll
        for (int j = 0; j < 8; ++j) acc[k * 8 + j] += wv * b2f(v[j]);
      }
    }
    float inv = 1.f / den;
    unsigned short* op = &aout[(nb + d) * DH + cbase];
    #pragma unroll
    for (int k = 0; k < 6; ++k) {
      u16x8 o;
      #pragma unroll
      for (int j = 0; j < 8; ++j) o[j] = f2b(acc[k * 8 + j] * inv + s_bg[cbase + k * 8 + j]);
      *(u16x8*)&op[k * 8] = o;
    }
  }
}

// ---- fused GRU, persistent blocks, weights in LDS ----
__global__ __launch_bounds__(512, 2) void k_gru(
    const unsigned short* __restrict__ ab, unsigned short* __restrict__ xb,
    const unsigned short* __restrict__ WT, const float* __restrict__ bc) {
  __shared__ __align__(16) unsigned short sW[6 * DH * WS];   // 115200 B
  __shared__ __align__(16) unsigned short sX[128 * WS];      // 25600 B
  const int t = threadIdx.x, w = t >> 6, l = t & 63, li = l & 15, lh = l >> 4;
  const int wr = w >> 1, wc = w & 1;
  // stage weights: order Wr0,Wr1,Wz0,Wz1,Wh0,Wh1 (WT idx 3,4,1,2,5,6)
  #pragma unroll
  for (int m = 0; m < 6; ++m) {
    const int srcm = (m == 0) ? 3 : (m == 1) ? 4 : (m == 2) ? 1 : (m == 3) ? 2 : (m == 4) ? 5 : 6;
    const unsigned short* srcp = WT + srcm * DH * DH;
    for (int i = t; i < DH * 12; i += 512) {
      int r = i / 12, c8 = i - r * 12;
      *(int4*)&sW[(m * DH + r) * WS + c8 * 8] = *(const int4*)&srcp[r * DH + c8 * 8];
    }
  }
  float zb_[3], rb_[3], hb_[3];
  #pragma unroll
  for (int ct = 0; ct < 3; ++ct) {
    const int col = wc * 48 + ct * 16 + li;
    zb_[ct] = bc[col]; rb_[ct] = bc[DH + col]; hb_[ct] = bc[2 * DH + col];
  }

  for (int tile = 0; tile < 4; ++tile) {
    const int nb0 = (blockIdx.x * 4 + tile) * 128;
    __syncthreads();
    #pragma unroll
    for (int j = 0; j < 3; ++j) {
      int idx = t + 512 * j;
      int row = idx / 12, ch = idx - row * 12;
      *(int4*)&sX[row * WS + ch * 8] = *(const int4*)&xb[(nb0 + row) * DH + ch * 8];
    }
    __syncthreads();
    bf16x8 aA[2][3], aX[2][3];
    #pragma unroll
    for (int rt = 0; rt < 2; rt++)
      #pragma unroll
      for (int ks = 0; ks < 3; ks++) {
        const int row = wr * 32 + rt * 16 + li;
        const int ko = lh * 8 + ks * 32;
        aA[rt][ks] = *(const bf16x8*)&ab[(nb0 + row) * DH + ko];
        aX[rt][ks] = *(const bf16x8*)&sX[row * WS + ko];
      }
    float xo[2][3][4];
    #pragma unroll
    for (int rt = 0; rt < 2; rt++)
      #pragma unroll
      for (int ct = 0; ct < 3; ct++)
        #pragma unroll
        for (int r = 0; r < 4; r++)
          xo[rt][ct][r] = b2f(sX[(wr * 32 + rt * 16 + lh * 4 + r) * WS + wc * 48 + ct * 16 + li]);
    f32x4 accR[2][3], accZ[2][3];
    #pragma unroll
    for (int rt = 0; rt < 2; rt++)
      #pragma unroll
      for (int ct = 0; ct < 3; ct++) { accR[rt][ct] = (f32x4)0.f; accZ[rt][ct] = (f32x4)0.f; }
    #pragma unroll
    for (int ks = 0; ks < 3; ks++) {
      const int ko = lh * 8 + ks * 32;
      #pragma unroll
      for (int ct = 0; ct < 3; ct++) {
        const int wrow = wc * 48 + ct * 16 + li;
        bf16x8 w_r0 = *(const bf16x8*)&sW[(0 * DH + wrow) * WS + ko];
        bf16x8 w_r1 = *(const bf16x8*)&sW[(1 * DH + wrow) * WS + ko];
        bf16x8 w_z0 = *(const bf16x8*)&sW[(2 * DH + wrow) * WS + ko];
        bf16x8 w_z1 = *(const bf16x8*)&sW[(3 * DH + wrow) * WS + ko];
        #pragma unroll
        for (int rt = 0; rt < 2; rt++) {
          accR[rt][ct] = MFMA16(aA[rt][ks], w_r0, accR[rt][ct]);
          accR[rt][ct] = MFMA16(aX[rt][ks], w_r1, accR[rt][ct]);
          accZ[rt][ct] = MFMA16(aA[rt][ks], w_z0, accZ[rt][ct]);
          accZ[rt][ct] = MFMA16(aX[rt][ks], w_z1, accZ[rt][ct]);
        }
      }
    }
    __syncthreads();
    #pragma unroll
    for (int rt = 0; rt < 2; rt++)
      #pragma unroll
      for (int ct = 0; ct < 3; ct++) {
        const int col = wc * 48 + ct * 16 + li;
        #pragma unroll
        for (int r = 0; r < 4; r++) {
          float rv = sigm(accR[rt][ct][r] + rb_[ct]);
          sX[(wr * 32 + rt * 16 + lh * 4 + r) * WS + col] = f2b(xo[rt][ct][r] * rv);
        }
      }
    __syncthreads();
    bf16x8 aU[2][3];
    #pragma unroll
    for (int rt = 0; rt < 2; rt++)
      #pragma unroll
      for (int ks = 0; ks < 3; ks++)
        aU[rt][ks] = *(const bf16x8*)&sX[(wr * 32 + rt * 16 + li) * WS + lh * 8 + ks * 32];
    __syncthreads();
    f32x4 accH[2][3];
    #pragma unroll
    for (int rt = 0; rt < 2; rt++)
      #pragma unroll
      for (int ct = 0; ct < 3; ct++) accH[rt][ct] = (f32x4)0.f;
    #pragma unroll
    for (int ks = 0; ks < 3; ks++) {
      const int ko = lh * 8 + ks * 32;
      #pragma unroll
      for (int ct = 0; ct < 3; ct++) {
        const int wrow = wc * 48 + ct * 16 + li;
        bf16x8 w_h0 = *(const bf16x8*)&sW[(4 * DH + wrow) * WS + ko];
        bf16x8 w_h1 = *(const bf16x8*)&sW[(5 * DH + wrow) * WS + ko];
        #pragma unroll
        for (int rt = 0; rt < 2; rt++) {
          accH[rt][ct] = MFMA16(aA[rt][ks], w_h0, accH[rt][ct]);
          accH[rt][ct] = MFMA16(aU[rt][ks], w_h1, accH[rt][ct]);
        }
      }
    }
    #pragma unroll
    for (int rt = 0; rt < 2; rt++)
      #pragma unroll
      for (int ct = 0; ct < 3; ct++) {
        const int col = wc * 48 + ct * 16 + li;
        #pragma unroll
        for (int r = 0; r < 4; r++) {
          float z = sigm(accZ[rt][ct][r] + zb_[ct]);
          float hh = ftanh(accH[rt][ct][r] + hb_[ct]);
          float xn = hh * z + xo[rt][ct][r] * (1.f - z);
          sX[(wr * 32 + rt * 16 + lh * 4 + r) * WS + col] = f2b(xn);
        }
      }
    __syncthreads();
    #pragma unroll
    for (int j = 0; j < 3; ++j) {
      int idx = t + 512 * j;
      int row = idx / 12, ch = idx - row * 12;
      *(int4*)&xb[(nb0 + row) * DH + ch * 8] = *(const int4*)&sX[row * WS + ch * 8];
    }
  }
}

// ---- readout: y = tanh(xb @ Wemb); pool max+mean; out = pooled @ Wmlp (W in LDS) ----
__global__ __launch_bounds__(256) void k_readout(
    const unsigned short* __restrict__ xb, const unsigned short* __restrict__ WembT,
    const float* __restrict__ Wmlp, float* __restrict__ out) {
  __shared__ __align__(16) unsigned short sW[DH * WS];   // 19200 B
  __shared__ float pmaxs[4][DH], psums[4][DH];
  __shared__ float spool[DH];
  const int g = blockIdx.x, t = threadIdx.x, w = t >> 6, l = t & 63, li = l & 15, lh = l >> 4;
  const int wbase = g * LGRAPH + w * 64;
  for (int i = t; i < DH * 12; i += 256) {
    int r = i / 12, c8 = i - r * 12;
    *(int4*)&sW[r * WS + c8 * 8] = *(const int4*)&WembT[r * DH + c8 * 8];
  }
  __syncthreads();
  f32x4 acc[4][6];
  #pragma unroll
  for (int rt = 0; rt < 4; rt++)
    #pragma unroll
    for (int ct = 0; ct < 6; ct++) acc[rt][ct] = (f32x4)0.f;
  #pragma unroll
  for (int ks = 0; ks < 3; ks++) {
    const int ko = lh * 8 + ks * 32;
    bf16x8 aA[4];
    #pragma unroll
    for (int rt = 0; rt < 4; rt++)
      aA[rt] = *(const bf16x8*)&xb[(wbase + rt * 16 + li) * DH + ko];
    #pragma unroll
    for (int ct = 0; ct < 6; ct++) {
      bf16x8 bB = *(const bf16x8*)&sW[(ct * 16 + li) * WS + ko];
      #pragma unroll
      for (int rt = 0; rt < 4; rt++) acc[rt][ct] = MFMA16(aA[rt], bB, acc[rt][ct]);
    }
  }
  float pm[6], psu[6];
  #pragma unroll
  for (int ct = 0; ct < 6; ct++) {
    float mx = -1e30f, sm = 0.f;
    #pragma unroll
    for (int rt = 0; rt < 4; rt++)
      #pragma unroll
      for (int r = 0; r < 4; r++) {
        float y = ftanh(acc[rt][ct][r]);
        mx = fmaxf(mx, y);
        sm += y;
      }
    pm[ct] = mx; psu[ct] = sm;
  }
  #pragma unroll
  for (int ct = 0; ct < 6; ct++) {
    pm[ct] = fmaxf(pm[ct], __shfl_xor(pm[ct], 16));
    psu[ct] += __shfl_xor(psu[ct], 16);
    pm[ct] = fmaxf(pm[ct], __shfl_xor(pm[ct], 32));
    psu[ct] += __shfl_xor(psu[ct], 32);
  }
  if (lh == 0) {
    #pragma unroll
    for (int ct = 0; ct < 6; ct++) {
      pmaxs[w][ct * 16 + li] = pm[ct];
      psums[w][ct * 16 + li] = psu[ct];
    }
  }
  __syncthreads();
  if (t < DH) {
    float mx = fmaxf(fmaxf(pmaxs[0][t], pmaxs[1][t]), fmaxf(pmaxs[2][t], pmaxs[3][t]));
    float sm = psums[0][t] + psums[1][t] + psums[2][t] + psums[3][t];
    spool[t] = mx + sm * (1.f / LGRAPH);
  }
  __syncthreads();
  if (t < NCLS) {
    float a = 0.f;
    for (int k = 0; k < DH; ++k) a += spool[k] * Wmlp[k * NCLS + t];
    out[g * NCLS + t] = a;
  }
}

extern "C" void kernel_launch(void* const* d_in, const int* in_sizes, int n_in,
                              void* d_out, int out_size, void* d_ws, size_t ws_size,
                              hipStream_t stream) {
  const int*   node_ids = (const int*)d_in[0];
  const int*   src      = (const int*)d_in[1];
  const int*   dst      = (const int*)d_in[2];
  const float* embed    = (const float*)d_in[3];
  const float* We   = (const float*)d_in[4];
  const float* be   = (const float*)d_in[5];
  const float* Wg   = (const float*)d_in[6];
  const float* att_src = (const float*)d_in[7];
  const float* att_dst = (const float*)d_in[8];
  const float* bg   = (const float*)d_in[9];
  const float* Wz0  = (const float*)d_in[10];
  const float* bz0  = (const float*)d_in[11];
  const float* Wz1  = (const float*)d_in[12];
  const float* bz1  = (const float*)d_in[13];
  const float* Wr0  = (const float*)d_in[14];
  const float* br0  = (const float*)d_in[15];
  const float* Wr1  = (const float*)d_in[16];
  const float* br1  = (const float*)d_in[17];
  const float* Wh0  = (const float*)d_in[18];
  const float* bh0  = (const float*)d_in[19];
  const float* Wh1  = (const float*)d_in[20];
  const float* bh1  = (const float*)d_in[21];
  const float* Wemb = (const float*)d_in[22];
  const float* Wmlp = (const float*)d_in[23];
  float* out = (float*)d_out;

  char* w_ = (char*)d_ws;
  unsigned short* xb   = (unsigned short*)(w_ + 0);           // 25,165,824 B
  unsigned short* ab   = (unsigned short*)(w_ + 25165824);    // 25,165,824 B
  unsigned short* h    = (unsigned short*)(w_ + 50331648);    // 25,165,824 B
  unsigned short* Tb   = (unsigned short*)(w_ + 75497472);    // 9,609,216 B
  float*          a_s  = (float*)(w_ + 85106688);             // 524,288 B
  float*          a_d  = (float*)(w_ + 85630976);             // 524,288 B
  unsigned short* WT   = (unsigned short*)(w_ + 86155264);    // 147,456 B
  unsigned short* WeT  = (unsigned short*)(w_ + 86302720);    // 61,440 B
  float*          bc   = (float*)(w_ + 86364160);             // 1,152 B

  unsigned short* WgT  = WT + 0 * DH * DH;
  unsigned short* WembT= WT + 7 * DH * DH;

  hipLaunchKernelGGL(k_prep_w, dim3(10), dim3(256), 0, stream,
                     Wg, Wz0, Wz1, Wr0, Wr1, Wh0, Wh1, Wemb, We,
                     bz0, bz1, br0, br1, bh0, bh1, WT, WeT, bc);
  hipLaunchKernelGGL(k_emb_mm, dim3(EMB_ROWS / 128), dim3(256), 0, stream, embed, WeT, Tb);
  hipLaunchKernelGGL(k_gather, dim3(2048), dim3(256), 0, stream, node_ids, Tb, be, xb);
  for (int s = 0; s < 2; ++s) {
    hipLaunchKernelGGL(k_h, dim3(NNODES / 128), dim3(256), 0, stream,
                       xb, WgT, att_src, att_dst, h, a_s, a_d);
    hipLaunchKernelGGL(k_att, dim3(BGRAPH), dim3(512), 0, stream,
                       src, dst, h, a_s, a_d, bg, ab);
    hipLaunchKernelGGL(k_gru, dim3(256), dim3(512), 0, stream, ab, xb, WT, bc);
  }
  hipLaunchKernelGGL(k_readout, dim3(BGRAPH), dim3(256), 0, stream, xb, WembT, Wmlp, out);
}